// Round 6
// baseline (282.544 us; speedup 1.0000x reference)
//
#include <hip/hip_runtime.h>
#include <hip/hip_bf16.h>

#define LOG2E 1.4426950408889634f

typedef short short8 __attribute__((ext_vector_type(8)));
typedef float floatx4 __attribute__((ext_vector_type(4)));

__device__ __forceinline__ floatx4 mfma16(short8 a, short8 b, floatx4 c) {
    return __builtin_amdgcn_mfma_f32_16x16x32_bf16(a, b, c, 0, 0, 0);
}

__device__ __forceinline__ float fexp2(float x) { return __builtin_amdgcn_exp2f(x); }

// fast RNE fp32->bf16 (finite inputs only)
__device__ __forceinline__ short f2bf(float f) {
    unsigned u = __builtin_bit_cast(unsigned, f);
    u += 0x7FFFu + ((u >> 16) & 1u);
    return (short)(u >> 16);
}
// pack two fp32 -> (bf16(a) | bf16(b)<<16), round-half-up (+0x8000) + byte
// perm. Differs from RNE only on exact ties (low16==0x8000, p~2^-16),
// unbiased unlike v_cvt_pk_bf16_f32 (RTZ — broke the absmax gate in R4).
// 3 VALU ops vs 11 for the full RNE pair.
__device__ __forceinline__ unsigned bfpack(float a, float b) {
    unsigned ua = __builtin_bit_cast(unsigned, a) + 0x8000u;
    unsigned ub = __builtin_bit_cast(unsigned, b) + 0x8000u;
    // sel 0x07060302: result = [ua.b2, ua.b3, ub.b2, ub.b3] = (ua>>16)|(ub&0xFFFF0000)
    return __builtin_amdgcn_perm(ub, ua, 0x07060302u);
}
__device__ __forceinline__ float bf2f(short s) {
    unsigned u = ((unsigned)(unsigned short)s) << 16;
    return __builtin_bit_cast(float, u);
}

// async global->LDS, 16B per lane
__device__ __forceinline__ void glds16(const void* g, void* l) {
    __builtin_amdgcn_global_load_lds(
        (const __attribute__((address_space(1))) void*)g,
        (__attribute__((address_space(3))) void*)l, 16, 0, 0);
}

__device__ __forceinline__ short8 cvt8(const float* __restrict__ p) {
    float4 a = *reinterpret_cast<const float4*>(p);
    float4 b = *reinterpret_cast<const float4*>(p + 4);
    short8 r;
    r[0] = f2bf(a.x); r[1] = f2bf(a.y); r[2] = f2bf(a.z); r[3] = f2bf(a.w);
    r[4] = f2bf(b.x); r[5] = f2bf(b.y); r[6] = f2bf(b.z); r[7] = f2bf(b.w);
    return r;
}

// ---------------------------------------------------------------------------
__global__ __launch_bounds__(256) void cvt_x_kernel(
    const float* __restrict__ in, short* __restrict__ out, int n8)
{
    int i = blockIdx.x * blockDim.x + threadIdx.x;
    if (i < n8)
        *reinterpret_cast<short8*>(out + (size_t)i * 8) = cvt8(in + (size_t)i * 8);
}

// ---------------------------------------------------------------------------
__global__ __launch_bounds__(256) void cvt_wt_kernel(
    const float* __restrict__ W0, const float* __restrict__ W1,
    const float* __restrict__ W2, const float* __restrict__ W3,
    const float* __restrict__ W4, short* __restrict__ Wt)
{
    __shared__ short T[64 * 66];
    const int w = blockIdx.z;
    const float* W = (w == 0) ? W0 : (w == 1) ? W1 : (w == 2) ? W2 : (w == 3) ? W3 : W4;
    short* dst = Wt + (size_t)w * 1024 * 1024;
    const int kb = blockIdx.y * 64, nb = blockIdx.x * 64;
    const int t = threadIdx.x;
    const int r = t >> 2, c4 = (t & 3) * 16;
    *reinterpret_cast<short8*>(T + r * 66 + c4)     = cvt8(W + (size_t)(kb + r) * 1024 + nb + c4);
    *reinterpret_cast<short8*>(T + r * 66 + c4 + 8) = cvt8(W + (size_t)(kb + r) * 1024 + nb + c4 + 8);
    __syncthreads();
    short8 o0, o1;
    #pragma unroll
    for (int j = 0; j < 8; ++j) o0[j] = T[(c4 + j) * 66 + r];
    #pragma unroll
    for (int j = 0; j < 8; ++j) o1[j] = T[(c4 + 8 + j) * 66 + r];
    *reinterpret_cast<short8*>(dst + (size_t)(nb + r) * 1024 + kb + c4)     = o0;
    *reinterpret_cast<short8*>(dst + (size_t)(nb + r) * 1024 + kb + c4 + 8) = o1;
}

// ---------------------------------------------------------------------------
// flag_scan: any-nonzero over amask + kpm -> *flag. Runs before mask_prep
// so the zero-mask path skips the 32 MB Mc write entirely.
// ---------------------------------------------------------------------------
__global__ __launch_bounds__(256) void flag_scan(
    const float* __restrict__ amask, const unsigned char* __restrict__ kpm,
    int* __restrict__ flag)
{
    const int i = blockIdx.x * 256 + threadIdx.x;
    const float4* a4 = reinterpret_cast<const float4*>(amask);
    float4 v0 = a4[(size_t)i * 2];
    float4 v1 = a4[(size_t)i * 2 + 1];
    bool nz = (v0.x != 0.f) | (v0.y != 0.f) | (v0.z != 0.f) | (v0.w != 0.f)
            | (v1.x != 0.f) | (v1.y != 0.f) | (v1.z != 0.f) | (v1.w != 0.f);
    if (blockIdx.x == 0) {
        const uint4* k4 = reinterpret_cast<const uint4*>(kpm);
        uint4 kv = k4[threadIdx.x];          // 256 * 16B = 4096B = full kpm
        nz |= ((kv.x | kv.y | kv.z | kv.w) != 0u);
    }
    if (__ballot(nz) && ((threadIdx.x & 63) == 0)) atomicOr(flag, 1);
}

// ---------------------------------------------------------------------------
// mask prepass (masked path only): Mc[b][q][p] = amask[q][j]*LOG2E +
// (kpm[b][j] ? -1e30 : 0) with pair-permuted cols. Early-exits when flag==0.
// ---------------------------------------------------------------------------
__global__ __launch_bounds__(256) void mask_prep(
    const float* __restrict__ amask, const unsigned char* __restrict__ kpm,
    float* __restrict__ Mc, const int* __restrict__ flag)
{
    if (*flag == 0) return;
    const int b = blockIdx.z, q = blockIdx.y;
    const int p0 = threadIdx.x * 8;
    float o[8];
    #pragma unroll
    for (int i = 0; i < 8; ++i) {
        int p = p0 + i;
        int j = (p & ~31) | ((p >> 1) & 15) | ((p & 1) << 4);
        unsigned char kb = kpm[b * 2048 + j];
        float a = amask[(size_t)q * 2048 + j];
        o[i] = a * LOG2E + (kb ? -1.0e30f : 0.f);
    }
    float* dst = Mc + ((size_t)b * 2048 + q) * 2048 + p0;
    *reinterpret_cast<float4*>(dst)     = make_float4(o[0], o[1], o[2], o[3]);
    *reinterpret_cast<float4*>(dst + 4) = make_float4(o[4], o[5], o[6], o[7]);
}

// ---------------------------------------------------------------------------
// 256x256-tile depth-3 pipelined GEMM core: 8 waves (512 thr), BK=32,
// 4 LDS buffers (128 KiB), counted vmcnt (never 0 in main loop), raw
// s_barrier with sched_barrier fences.
// ---------------------------------------------------------------------------
__device__ __forceinline__ void gemm_core256p(
    const short* __restrict__ A, const short* __restrict__ Wt,
    int mbase, int nbase, short* Asm, short* Bsm, floatx4 (&acc)[8][4])
{
    const int tid = threadIdx.x;
    const int lane = tid & 63, wid = tid >> 6;
    const int L15 = lane & 15, g = lane >> 4;
    const int wrow = (wid >> 2) * 128, wcol = (wid & 3) * 64;

    const int rl4 = lane >> 2, c4 = lane & 3;
    const int R0 = wid * 32;
    const short* aG = A  + (size_t)(mbase + R0 + rl4) * 1024 + c4 * 8;
    const short* bG = Wt + (size_t)(nbase + R0 + rl4) * 1024 + c4 * 8;

#define STAGE(t_) do {                                                        \
        const int sl_ = (t_) & 3;                                             \
        glds16(aG + (size_t)(t_) * 32,         Asm + sl_ * 8192 + R0 * 32);   \
        glds16(aG + (size_t)(t_) * 32 + 16384, Asm + sl_ * 8192 + R0 * 32 + 512); \
        glds16(bG + (size_t)(t_) * 32,         Bsm + sl_ * 8192 + R0 * 32);   \
        glds16(bG + (size_t)(t_) * 32 + 16384, Bsm + sl_ * 8192 + R0 * 32 + 512); \
    } while (0)

#define COMP(t_) do {                                                         \
        const int sl_ = (t_) & 3;                                             \
        const short* Ab_ = Asm + sl_ * 8192;                                  \
        const short* Bb_ = Bsm + sl_ * 8192;                                  \
        short8 af_[8], bf_[4];                                                \
        _Pragma("unroll")                                                     \
        for (int mt = 0; mt < 8; ++mt)                                        \
            af_[mt] = *reinterpret_cast<const short8*>(Ab_ + (wrow + mt * 16 + L15) * 32 + g * 8); \
        _Pragma("unroll")                                                     \
        for (int nt = 0; nt < 4; ++nt)                                        \
            bf_[nt] = *reinterpret_cast<const short8*>(Bb_ + (wcol + nt * 16 + L15) * 32 + g * 8); \
        __builtin_amdgcn_s_setprio(1);                                        \
        _Pragma("unroll")                                                     \
        for (int mt = 0; mt < 8; ++mt)                                        \
            _Pragma("unroll")                                                 \
            for (int nt = 0; nt < 4; ++nt)                                    \
                acc[mt][nt] = mfma16(af_[mt], bf_[nt], acc[mt][nt]);          \
        __builtin_amdgcn_s_setprio(0);                                        \
    } while (0)

#define BARRIER_SB() do {                                                     \
        __builtin_amdgcn_sched_barrier(0);                                    \
        __builtin_amdgcn_s_barrier();                                         \
        __builtin_amdgcn_sched_barrier(0);                                    \
    } while (0)

    STAGE(0); STAGE(1); STAGE(2);

    for (int t = 0; t < 29; ++t) {
        BARRIER_SB();
        STAGE(t + 3);
        asm volatile("s_waitcnt vmcnt(12)" ::: "memory");
        BARRIER_SB();
        COMP(t);
    }
    BARRIER_SB(); asm volatile("s_waitcnt vmcnt(8)" ::: "memory"); BARRIER_SB(); COMP(29);
    BARRIER_SB(); asm volatile("s_waitcnt vmcnt(4)" ::: "memory"); BARRIER_SB(); COMP(30);
    BARRIER_SB(); asm volatile("s_waitcnt vmcnt(0)" ::: "memory"); BARRIER_SB(); COMP(31);

#undef STAGE
#undef COMP
#undef BARRIER_SB
}

// ---------------------------------------------------------------------------
// 128x128-tile GEMM core (kept for out_gemm).
// ---------------------------------------------------------------------------
__device__ __forceinline__ void gemm_core(
    const short* __restrict__ A, const short* __restrict__ Wt,
    int mbase, int nbase, short* Asm, short* Bsm, floatx4 (&acc)[4][4])
{
    const int tid = threadIdx.x;
    const int lane = tid & 63, wid = tid >> 6;
    const int L15 = lane & 15, g = lane >> 4;
    const int wm = (wid >> 1) * 64, wn = (wid & 1) * 64;

    const int rowoff = lane >> 3;
    const int choff = ((lane & 7) ^ rowoff) * 8;
    const short* aP = A  + (size_t)(mbase + wid * 32 + rowoff) * 1024 + choff;
    const short* bP = Wt + (size_t)(nbase + wid * 32 + rowoff) * 1024 + choff;
    short* aL = Asm + wid * 2048;
    short* bL = Bsm + wid * 2048;

    const int xb = L15 & 7;
    const int s0 = (g ^ xb) * 8;
    const int s1 = ((g ^ 4) ^ xb) * 8;

    for (int kb = 0; kb < 1024; kb += 64) {
        __syncthreads();
        #pragma unroll
        for (int j = 0; j < 4; ++j) glds16(aP + kb + j * 8192, aL + j * 512);
        #pragma unroll
        for (int j = 0; j < 4; ++j) glds16(bP + kb + j * 8192, bL + j * 512);
        __syncthreads();
        #pragma unroll
        for (int ks = 0; ks < 2; ++ks) {
            const int so = ks ? s1 : s0;
            short8 af[4], bf[4];
            #pragma unroll
            for (int mt = 0; mt < 4; ++mt)
                af[mt] = *reinterpret_cast<const short8*>(Asm + (wm + mt * 16 + L15) * 64 + so);
            #pragma unroll
            for (int nt = 0; nt < 4; ++nt)
                bf[nt] = *reinterpret_cast<const short8*>(Bsm + (wn + nt * 16 + L15) * 64 + so);
            #pragma unroll
            for (int mt = 0; mt < 4; ++mt)
                #pragma unroll
                for (int nt = 0; nt < 4; ++nt)
                    acc[mt][nt] = mfma16(af[mt], bf[nt], acc[mt][nt]);
        }
    }
}

// ---------------------------------------------------------------------------
// Fused Q/K/V/G projections, 256^2 tiles, 512 threads, XCD chunk swizzle.
// Q written pre-scaled by 0.125*LOG2E. V^T pair-permuted, scalar RNE stores.
// ---------------------------------------------------------------------------
__global__ __launch_bounds__(512) void qkvg_gemm(
    const short* __restrict__ A, const short* __restrict__ Wt5,
    const float* __restrict__ b0, const float* __restrict__ b1,
    const float* __restrict__ b2, const float* __restrict__ b3,
    short* __restrict__ dQ, short* __restrict__ dK,
    short* __restrict__ dV, short* __restrict__ dG)
{
    __shared__ short Asm[4 * 8192];
    __shared__ short Bsm[4 * 8192];

    const int wg = blockIdx.x;
    const int swz = (wg & 7) * 32 + (wg >> 3);
    const int z = swz >> 6;
    const int rem = swz & 63;
    const int mbase = (rem >> 2) * 256, nbase = (rem & 3) * 256;

    floatx4 acc[8][4] = {};
    gemm_core256p(A, Wt5 + (size_t)z * 1048576, mbase, nbase, Asm, Bsm, acc);

    const int lane = threadIdx.x & 63, wid = threadIdx.x >> 6;
    const int L15 = lane & 15, g = lane >> 4;
    const int wrow = (wid >> 2) * 128, wcol = (wid & 3) * 64;
    const float* bz = (z == 0) ? b0 : (z == 1) ? b1 : (z == 2) ? b2 : b3;
    short* dst = (z == 0) ? dQ : (z == 1) ? dK : (z == 2) ? dV : dG;

    float bvv[4];
    #pragma unroll
    for (int nt = 0; nt < 4; ++nt) bvv[nt] = bz[nbase + wcol + nt * 16 + L15];

    if (z <= 1) {
        const float qsc = (z == 0) ? 0.125f * LOG2E : 1.0f;
        #pragma unroll
        for (int mt = 0; mt < 8; ++mt) {
            #pragma unroll
            for (int r = 0; r < 4; ++r) {
                int row = mbase + wrow + mt * 16 + g * 4 + r;
                int bb = row >> 11, s = row & 2047;
                #pragma unroll
                for (int nt = 0; nt < 4; ++nt) {
                    int col = nbase + wcol + nt * 16 + L15;
                    int hh = col >> 6, dh = col & 63;
                    dst[(((size_t)bb * 16 + hh) * 2048 + s) * 64 + dh] =
                        f2bf((acc[mt][nt][r] + bvv[nt]) * qsc);
                }
            }
        }
    } else if (z == 2) {
        #pragma unroll
        for (int nt = 0; nt < 4; ++nt) {
            int col = nbase + wcol + nt * 16 + L15;
            int hh = col >> 6, dh = col & 63;
            #pragma unroll
            for (int mt = 0; mt < 8; ++mt) {
                #pragma unroll
                for (int r = 0; r < 4; ++r) {
                    int row = mbase + wrow + mt * 16 + g * 4 + r;
                    int bb = row >> 11, s = row & 2047;
                    int sp = (s & ~31) | ((s & 15) << 1) | ((s >> 4) & 1);
                    dst[(((size_t)bb * 16 + hh) * 64 + dh) * 2048 + sp] =
                        f2bf(acc[mt][nt][r] + bvv[nt]);
                }
            }
        }
    } else {
        #pragma unroll
        for (int mt = 0; mt < 8; ++mt) {
            #pragma unroll
            for (int r = 0; r < 4; ++r) {
                int row = mbase + wrow + mt * 16 + g * 4 + r;
                #pragma unroll
                for (int nt = 0; nt < 4; ++nt) {
                    int col = nbase + wcol + nt * 16 + L15;
                    float e = fexp2(-(acc[mt][nt][r] + bvv[nt]) * LOG2E);
                    dst[(size_t)row * 1024 + col] = f2bf(__builtin_amdgcn_rcpf(1.0f + e));
                }
            }
        }
    }
}

// ---------------------------------------------------------------------------
__global__ __launch_bounds__(256) void out_gemm(
    const short* __restrict__ A, const short* __restrict__ Wt,
    const float* __restrict__ bias, float* __restrict__ out)
{
    __shared__ short Asm[128 * 64];
    __shared__ short Bsm[128 * 64];
    const int mbase = blockIdx.y * 128, nbase = blockIdx.x * 128;
    floatx4 acc[4][4] = {};
    gemm_core(A, Wt, mbase, nbase, Asm, Bsm, acc);

    const int lane = threadIdx.x & 63, wid = threadIdx.x >> 6;
    const int L15 = lane & 15, g = lane >> 4;
    const int wm = (wid >> 1) * 64, wn = (wid & 1) * 64;
    #pragma unroll
    for (int nt = 0; nt < 4; ++nt) {
        int col = nbase + wn + nt * 16 + L15;
        float bv = bias[col];
        #pragma unroll
        for (int mt = 0; mt < 4; ++mt)
            #pragma unroll
            for (int r = 0; r < 4; ++r) {
                int row = mbase + wm + mt * 16 + g * 4 + r;
                out[(size_t)row * 1024 + col] = acc[mt][nt][r] + bv;
            }
    }
}

// ---------------------------------------------------------------------------
// Flash attention: 512 threads, 8 waves x 16 q-rows, KVBLK=64, Q pre-scaled
// (scores arrive in log2 units), perm-packed P, zero-mask fast path.
// ---------------------------------------------------------------------------
template<bool MASKED>
__device__ __forceinline__ void flash_body(
    const short* __restrict__ Q, const short* __restrict__ K,
    const short* __restrict__ Vt, const short* __restrict__ G,
    const float* __restrict__ Mc, short* __restrict__ att,
    float* __restrict__ inv_l,
    short* Ksm, short* Vsm, short* Psm)
{
    const int tid = threadIdx.x;
    const int lane = tid & 63, wid = tid >> 6;
    const int L15 = lane & 15, g = lane >> 4;
    const int b = blockIdx.z, h = blockIdx.x;
    const int bh = b * 16 + h;
    const int qb = blockIdx.y * 128 + wid * 16;

    short8 aq0 = *reinterpret_cast<const short8*>(Q + ((size_t)bh * 2048 + qb + L15) * 64 + g * 8);
    short8 aq1 = *reinterpret_cast<const short8*>(Q + ((size_t)bh * 2048 + qb + L15) * 64 + 32 + g * 8);

    floatx4 O[4] = {};
    float l_r[4] = {0.f, 0.f, 0.f, 0.f};

    const int krow = lane >> 3;
    const int kch  = ((lane & 7) ^ krow) * 8;
    const bool isK = wid < 4;
    const int sw = isK ? wid : (wid - 4);
    const short* gP;
    if (isK) {
        gP = K + ((size_t)bh * 2048 + sw * 16 + krow) * 64 + kch;
    } else {
        const int vsc = (lane & 7) ^ krow;
        const int vhd = sw * 16 + 2 * krow + (vsc >> 2);
        gP = Vt + ((size_t)bh * 64 + vhd) * 2048 + (vsc & 3) * 8;
    }

    const int x7 = L15 & 7;
    const int sk0 = (g ^ x7) * 8, sk1 = ((g ^ 4) ^ x7) * 8;
    const int sv = (((L15 & 1) * 4 + g) ^ ((L15 >> 1) & 7)) * 8;
    const int vp = (L15 >> 1) * 64;

    short* Pw = Psm + wid * 1152;   // 16 rows x 72 shorts

    const float* mcP[4];
    float2 mc0[4], mc1[4];
    if (MASKED) {
        #pragma unroll
        for (int r = 0; r < 4; ++r) {
            mcP[r] = Mc + ((size_t)b * 2048 + qb + g * 4 + r) * 2048 + 2 * L15;
            mc0[r] = *reinterpret_cast<const float2*>(mcP[r]);
            mc1[r] = *reinterpret_cast<const float2*>(mcP[r] + 32);
        }
    }

    if (isK) {
        glds16(gP,       Ksm + sw * 1024);
        glds16(gP + 512, Ksm + sw * 1024 + 512);
    } else {
        glds16(gP,      Vsm + sw * 512);
        glds16(gP + 32, Vsm + 2048 + sw * 512);
    }

    for (int kb = 0; kb < 2048; kb += 64) {
        const int cur = (kb >> 6) & 1;
        __syncthreads();
        const int nb = kb + 64;
        const bool more = nb < 2048;
        float2 nmc0[4], nmc1[4];
        if (more) {
            if (isK) {
                glds16(gP + (size_t)nb * 64,       Ksm + (cur ^ 1) * 4096 + sw * 1024);
                glds16(gP + (size_t)nb * 64 + 512, Ksm + (cur ^ 1) * 4096 + sw * 1024 + 512);
            } else {
                glds16(gP + nb,      Vsm + (cur ^ 1) * 4096 + sw * 512);
                glds16(gP + nb + 32, Vsm + (cur ^ 1) * 4096 + 2048 + sw * 512);
            }
            if (MASKED) {
                #pragma unroll
                for (int r = 0; r < 4; ++r) {
                    nmc0[r] = *reinterpret_cast<const float2*>(mcP[r] + nb);
                    nmc1[r] = *reinterpret_cast<const float2*>(mcP[r] + nb + 32);
                }
            }
        }

        const short* Kb = Ksm + cur * 4096;
        floatx4 s[4];
        #pragma unroll
        for (int kt = 0; kt < 4; ++kt) {
            s[kt] = {};
            s[kt] = mfma16(aq0, *reinterpret_cast<const short8*>(Kb + (kt * 16 + L15) * 64 + sk0), s[kt]);
            s[kt] = mfma16(aq1, *reinterpret_cast<const short8*>(Kb + (kt * 16 + L15) * 64 + sk1), s[kt]);
        }

        #pragma unroll
        for (int r = 0; r < 4; ++r) {
            float e0 = fexp2(MASKED ? s[0][r] + mc0[r].x : s[0][r]);
            float e1 = fexp2(MASKED ? s[1][r] + mc0[r].y : s[1][r]);
            float e2 = fexp2(MASKED ? s[2][r] + mc1[r].x : s[2][r]);
            float e3 = fexp2(MASKED ? s[3][r] + mc1[r].y : s[3][r]);
            l_r[r] += (e0 + e1) + (e2 + e3);
            *reinterpret_cast<unsigned*>(&Pw[(g * 4 + r) * 72 + 2 * L15])      = bfpack(e0, e1);
            *reinterpret_cast<unsigned*>(&Pw[(g * 4 + r) * 72 + 32 + 2 * L15]) = bfpack(e2, e3);
        }
        short8 ap0 = *reinterpret_cast<const short8*>(&Pw[L15 * 72 + g * 8]);
        short8 ap1 = *reinterpret_cast<const short8*>(&Pw[L15 * 72 + 32 + g * 8]);
        const short* Vb0 = Vsm + cur * 4096;
        const short* Vb1 = Vb0 + 2048;
        #pragma unroll
        for (int t = 0; t < 4; ++t) {
            O[t] = mfma16(ap0, *reinterpret_cast<const short8*>(Vb0 + t * 512 + vp + sv), O[t]);
            O[t] = mfma16(ap1, *reinterpret_cast<const short8*>(Vb1 + t * 512 + vp + sv), O[t]);
        }

        if (MASKED && more) {
            #pragma unroll
            for (int r = 0; r < 4; ++r) { mc0[r] = nmc0[r]; mc1[r] = nmc1[r]; }
        }
    }

    float inv[4];
    #pragma unroll
    for (int r = 0; r < 4; ++r) {
        float ls = l_r[r];
        ls += __shfl_xor(ls, 1);
        ls += __shfl_xor(ls, 2);
        ls += __shfl_xor(ls, 4);
        ls += __shfl_xor(ls, 8);
        inv[r] = 1.0f / ls;
        if (L15 == 0) inv_l[(size_t)bh * 2048 + qb + g * 4 + r] = inv[r];
    }
    #pragma unroll
    for (int t = 0; t < 4; ++t) {
        int col = h * 64 + t * 16 + L15;
        #pragma unroll
        for (int r = 0; r < 4; ++r) {
            size_t qr = qb + g * 4 + r;
            float gt = bf2f(G[((size_t)b * 2048 + qr) * 1024 + col]);
            att[((size_t)b * 2048 + qr) * 1024 + col] = f2bf(O[t][r] * inv[r] * gt);
        }
    }
}

__global__ __launch_bounds__(512, 4) void flash_attn(
    const short* __restrict__ Q, const short* __restrict__ K,
    const short* __restrict__ Vt, const short* __restrict__ G,
    const float* __restrict__ Mc, const int* __restrict__ flag,
    short* __restrict__ att, float* __restrict__ inv_l)
{
    __shared__ short Ksm[2 * 4096];
    __shared__ short Vsm[2 * 4096];
    __shared__ short Psm[8 * 1152];
    if (*flag)
        flash_body<true>(Q, K, Vt, G, Mc, att, inv_l, Ksm, Vsm, Psm);
    else
        flash_body<false>(Q, K, Vt, G, Mc, att, inv_l, Ksm, Vsm, Psm);
}

// ---------------------------------------------------------------------------
// avg_attn body, templated on MASKED (unmasked path = bare exp2, no pm).
// Q is pre-scaled, so no per-score multiply.
// ---------------------------------------------------------------------------
template<bool MASKED>
__device__ __forceinline__ void avg_body(
    const short* __restrict__ Q, const short* __restrict__ K,
    const float* __restrict__ inv_l, float* mca, short* KsmBase)
{
    const int tid = threadIdx.x;
    const int lane = tid & 63, wid = tid >> 6;
    const int L15 = lane & 15, g = lane >> 4;
    const int b = blockIdx.z;
    const int qb = blockIdx.y * 64 + wid * 16;
    const int ks = blockIdx.x * 128;

    float pm[4][2][4];
    if (MASKED) {
        #pragma unroll
        for (int c = 0; c < 4; ++c)
            #pragma unroll
            for (int r = 0; r < 4; ++r) {
                size_t qr = qb + g * 4 + r;
                float2 m = *reinterpret_cast<const float2*>(
                    mca + ((size_t)b * 2048 + qr) * 2048 + ks + c * 32 + 2 * L15);
                pm[c][0][r] = m.x;
                pm[c][1][r] = m.y;
            }
    }
    float av[4][2][4] = {};

    const int rowoff = lane >> 3;
    const int choff = ((lane & 7) ^ rowoff) * 8;
    const int x7 = L15 & 7;
    const int sk0 = (g ^ x7) * 8, sk1 = ((g ^ 4) ^ x7) * 8;
    short* kL[2] = { KsmBase + wid * 2048, KsmBase + 8192 + wid * 2048 };

    {
        const short* p = K + ((size_t)(b * 16) * 2048 + ks + wid * 32 + rowoff) * 64 + choff;
        #pragma unroll
        for (int j = 0; j < 4; ++j) glds16(p + j * 512, kL[0] + j * 512);
    }
    short8 aq0 = *reinterpret_cast<const short8*>(Q + ((size_t)(b * 16) * 2048 + qb + L15) * 64 + g * 8);
    short8 aq1 = *reinterpret_cast<const short8*>(Q + ((size_t)(b * 16) * 2048 + qb + L15) * 64 + 32 + g * 8);
    float iv[4];
    #pragma unroll
    for (int r = 0; r < 4; ++r) iv[r] = inv_l[(size_t)(b * 16) * 2048 + qb + g * 4 + r];

    for (int h = 0; h < 16; ++h) {
        __syncthreads();
        short8 naq0, naq1;
        float niv[4];
        if (h < 15) {
            int nbh = b * 16 + h + 1;
            const short* p = K + ((size_t)nbh * 2048 + ks + wid * 32 + rowoff) * 64 + choff;
            #pragma unroll
            for (int j = 0; j < 4; ++j) glds16(p + j * 512, kL[(h + 1) & 1] + j * 512);
            naq0 = *reinterpret_cast<const short8*>(Q + ((size_t)nbh * 2048 + qb + L15) * 64 + g * 8);
            naq1 = *reinterpret_cast<const short8*>(Q + ((size_t)nbh * 2048 + qb + L15) * 64 + 32 + g * 8);
            #pragma unroll
            for (int r = 0; r < 4; ++r) niv[r] = inv_l[(size_t)nbh * 2048 + qb + g * 4 + r];
        }

        const short* Kb = KsmBase + (h & 1) * 8192;
        #pragma unroll
        for (int c = 0; c < 4; ++c) {
            const short* kbase = Kb + c * 32 * 64;
            floatx4 s0 = {}, s1 = {};
            s0 = mfma16(aq0, *reinterpret_cast<const short8*>(kbase + L15 * 64 + sk0), s0);
            s0 = mfma16(aq1, *reinterpret_cast<const short8*>(kbase + L15 * 64 + sk1), s0);
            s1 = mfma16(aq0, *reinterpret_cast<const short8*>(kbase + (16 + L15) * 64 + sk0), s1);
            s1 = mfma16(aq1, *reinterpret_cast<const short8*>(kbase + (16 + L15) * 64 + sk1), s1);
            #pragma unroll
            for (int r = 0; r < 4; ++r) {
                av[c][0][r] += fexp2(MASKED ? s0[r] + pm[c][0][r] : s0[r]) * iv[r];
                av[c][1][r] += fexp2(MASKED ? s1[r] + pm[c][1][r] : s1[r]) * iv[r];
            }
        }
        if (h < 15) {
            aq0 = naq0; aq1 = naq1;
            #pragma unroll
            for (int r = 0; r < 4; ++r) iv[r] = niv[r];
        }
    }
    #pragma unroll
    for (int c = 0; c < 4; ++c)
        #pragma unroll
        for (int t = 0; t < 2; ++t)
            #pragma unroll
            for (int r = 0; r < 4; ++r) {
                size_t qr = qb + g * 4 + r;
                int col = ks + c * 32 + t * 16 + L15;
                mca[((size_t)b * 2048 + qr) * 2048 + col] = av[c][t][r] * 0.0625f;
            }
}

__global__ __launch_bounds__(256) void avg_attn_kernel(
    const short* __restrict__ Q, const short* __restrict__ K,
    const float* __restrict__ inv_l, float* mca, const int* __restrict__ flag)
{
    __shared__ short Ksm[2 * 128 * 64];
    if (*flag)
        avg_body<true>(Q, K, inv_l, mca, Ksm);
    else
        avg_body<false>(Q, K, inv_l, mca, Ksm);
}

// ---------------------------------------------------------------------------
extern "C" void kernel_launch(void* const* d_in, const int* in_sizes, int n_in,
                              void* d_out, int out_size, void* d_ws, size_t ws_size,
                              hipStream_t stream)
{
    const float* x  = (const float*)d_in[0];
    const float* amask = (const float*)d_in[1];
    const unsigned char* kpm = (const unsigned char*)d_in[2];
    const float* Wq = (const float*)d_in[3];
    const float* bq = (const float*)d_in[4];
    const float* Wk = (const float*)d_in[5];
    const float* bk = (const float*)d_in[6];
    const float* Wv = (const float*)d_in[7];
    const float* bv = (const float*)d_in[8];
    const float* Wg = (const float*)d_in[9];
    const float* bg = (const float*)d_in[10];
    const float* Wo = (const float*)d_in[11];
    const float* bo = (const float*)d_in[12];

    char* ws = (char*)d_ws;
    const size_t MB = 1u << 20;
    short* Xb    = (short*)(ws);                 // 8 MB bf16 x (reused as Att)
    short* Att   = Xb;
    short* Qw    = (short*)(ws + 8 * MB);        // [bh][2048][64] (pre-scaled)
    short* Kw    = (short*)(ws + 16 * MB);       // [bh][2048][64]
    short* Vt    = (short*)(ws + 24 * MB);       // [bh][64][2048] (key-permuted)
    short* Gw    = (short*)(ws + 32 * MB);       // bf16 gate [m][1024]
    short* Wt    = (short*)(ws + 40 * MB);       // 5 x [1024n][1024k] bf16
    float* stats = (float*)(ws + 50 * MB);       // inv_l (256 KB)
    int*   flagp = (int*)(ws + 50 * MB + 262144);

    float* outp = (float*)d_out;                 // [2][2048][1024]
    float* avgp = (float*)d_out + 4194304;       // [2][2048][2048]; holds Mc first

    hipMemsetAsync(flagp, 0, sizeof(int), stream);

    flag_scan<<<2048, 256, 0, stream>>>(amask, kpm, flagp);

    cvt_x_kernel<<<2048, 256, 0, stream>>>(x, Xb, 524288);
    cvt_wt_kernel<<<dim3(16, 16, 5), 256, 0, stream>>>(Wq, Wk, Wv, Wg, Wo, Wt);
    mask_prep<<<dim3(1, 2048, 2), 256, 0, stream>>>(amask, kpm, avgp, flagp);

    qkvg_gemm<<<256, 512, 0, stream>>>(Xb, Wt, bq, bk, bv, bg, Qw, Kw, Vt, Gw);

    flash_attn<<<dim3(16, 16, 2), 512, 0, stream>>>(Qw, Kw, Vt, Gw, avgp, flagp, Att, stats);

    avg_attn_kernel<<<dim3(16, 32, 2), 256, 0, stream>>>(Qw, Kw, stats, avgp, flagp);

    out_gemm<<<dim3(8, 32), 256, 0, stream>>>(Att, Wt + 4 * 1048576, bo, outp);
}

// Round 7
// 269.219 us; speedup vs baseline: 1.0495x; 1.0495x over previous
//
#include <hip/hip_runtime.h>
#include <hip/hip_bf16.h>

#define LOG2E 1.4426950408889634f

typedef short short8 __attribute__((ext_vector_type(8)));
typedef float floatx4 __attribute__((ext_vector_type(4)));

__device__ __forceinline__ floatx4 mfma16(short8 a, short8 b, floatx4 c) {
    return __builtin_amdgcn_mfma_f32_16x16x32_bf16(a, b, c, 0, 0, 0);
}

__device__ __forceinline__ float fexp2(float x) { return __builtin_amdgcn_exp2f(x); }

// fast RNE fp32->bf16 (finite inputs only)
__device__ __forceinline__ short f2bf(float f) {
    unsigned u = __builtin_bit_cast(unsigned, f);
    u += 0x7FFFu + ((u >> 16) & 1u);
    return (short)(u >> 16);
}
// pack two fp32 -> (bf16(a) | bf16(b)<<16), round-half-up (+0x8000) + byte
// perm. Differs from RNE only on exact ties (low16==0x8000, p~2^-16),
// unbiased unlike v_cvt_pk_bf16_f32 (RTZ — broke the absmax gate in R4).
__device__ __forceinline__ unsigned bfpack(float a, float b) {
    unsigned ua = __builtin_bit_cast(unsigned, a) + 0x8000u;
    unsigned ub = __builtin_bit_cast(unsigned, b) + 0x8000u;
    return __builtin_amdgcn_perm(ub, ua, 0x07060302u);
}
__device__ __forceinline__ float bf2f(short s) {
    unsigned u = ((unsigned)(unsigned short)s) << 16;
    return __builtin_bit_cast(float, u);
}

// async global->LDS, 16B per lane
__device__ __forceinline__ void glds16(const void* g, void* l) {
    __builtin_amdgcn_global_load_lds(
        (const __attribute__((address_space(1))) void*)g,
        (__attribute__((address_space(3))) void*)l, 16, 0, 0);
}

__device__ __forceinline__ short8 cvt8(const float* __restrict__ p) {
    float4 a = *reinterpret_cast<const float4*>(p);
    float4 b = *reinterpret_cast<const float4*>(p + 4);
    short8 r;
    r[0] = f2bf(a.x); r[1] = f2bf(a.y); r[2] = f2bf(a.z); r[3] = f2bf(a.w);
    r[4] = f2bf(b.x); r[5] = f2bf(b.y); r[6] = f2bf(b.z); r[7] = f2bf(b.w);
    return r;
}

// ---------------------------------------------------------------------------
__global__ __launch_bounds__(256) void cvt_x_kernel(
    const float* __restrict__ in, short* __restrict__ out, int n8)
{
    int i = blockIdx.x * blockDim.x + threadIdx.x;
    if (i < n8)
        *reinterpret_cast<short8*>(out + (size_t)i * 8) = cvt8(in + (size_t)i * 8);
}

// ---------------------------------------------------------------------------
__global__ __launch_bounds__(256) void cvt_wt_kernel(
    const float* __restrict__ W0, const float* __restrict__ W1,
    const float* __restrict__ W2, const float* __restrict__ W3,
    const float* __restrict__ W4, short* __restrict__ Wt)
{
    __shared__ short T[64 * 66];
    const int w = blockIdx.z;
    const float* W = (w == 0) ? W0 : (w == 1) ? W1 : (w == 2) ? W2 : (w == 3) ? W3 : W4;
    short* dst = Wt + (size_t)w * 1024 * 1024;
    const int kb = blockIdx.y * 64, nb = blockIdx.x * 64;
    const int t = threadIdx.x;
    const int r = t >> 2, c4 = (t & 3) * 16;
    *reinterpret_cast<short8*>(T + r * 66 + c4)     = cvt8(W + (size_t)(kb + r) * 1024 + nb + c4);
    *reinterpret_cast<short8*>(T + r * 66 + c4 + 8) = cvt8(W + (size_t)(kb + r) * 1024 + nb + c4 + 8);
    __syncthreads();
    short8 o0, o1;
    #pragma unroll
    for (int j = 0; j < 8; ++j) o0[j] = T[(c4 + j) * 66 + r];
    #pragma unroll
    for (int j = 0; j < 8; ++j) o1[j] = T[(c4 + 8 + j) * 66 + r];
    *reinterpret_cast<short8*>(dst + (size_t)(nb + r) * 1024 + kb + c4)     = o0;
    *reinterpret_cast<short8*>(dst + (size_t)(nb + r) * 1024 + kb + c4 + 8) = o1;
}

// ---------------------------------------------------------------------------
// flag_scan: any-nonzero over amask + kpm -> *flag.
// ---------------------------------------------------------------------------
__global__ __launch_bounds__(256) void flag_scan(
    const float* __restrict__ amask, const unsigned char* __restrict__ kpm,
    int* __restrict__ flag)
{
    const int i = blockIdx.x * 256 + threadIdx.x;
    const float4* a4 = reinterpret_cast<const float4*>(amask);
    float4 v0 = a4[(size_t)i * 2];
    float4 v1 = a4[(size_t)i * 2 + 1];
    bool nz = (v0.x != 0.f) | (v0.y != 0.f) | (v0.z != 0.f) | (v0.w != 0.f)
            | (v1.x != 0.f) | (v1.y != 0.f) | (v1.z != 0.f) | (v1.w != 0.f);
    if (blockIdx.x == 0) {
        const uint4* k4 = reinterpret_cast<const uint4*>(kpm);
        uint4 kv = k4[threadIdx.x];
        nz |= ((kv.x | kv.y | kv.z | kv.w) != 0u);
    }
    if (__ballot(nz) && ((threadIdx.x & 63) == 0)) atomicOr(flag, 1);
}

// ---------------------------------------------------------------------------
// mask prepass (masked path only). Early-exits when flag==0.
// ---------------------------------------------------------------------------
__global__ __launch_bounds__(256) void mask_prep(
    const float* __restrict__ amask, const unsigned char* __restrict__ kpm,
    float* __restrict__ Mc, const int* __restrict__ flag)
{
    if (*flag == 0) return;
    const int b = blockIdx.z, q = blockIdx.y;
    const int p0 = threadIdx.x * 8;
    float o[8];
    #pragma unroll
    for (int i = 0; i < 8; ++i) {
        int p = p0 + i;
        int j = (p & ~31) | ((p >> 1) & 15) | ((p & 1) << 4);
        unsigned char kb = kpm[b * 2048 + j];
        float a = amask[(size_t)q * 2048 + j];
        o[i] = a * LOG2E + (kb ? -1.0e30f : 0.f);
    }
    float* dst = Mc + ((size_t)b * 2048 + q) * 2048 + p0;
    *reinterpret_cast<float4*>(dst)     = make_float4(o[0], o[1], o[2], o[3]);
    *reinterpret_cast<float4*>(dst + 4) = make_float4(o[4], o[5], o[6], o[7]);
}

// ---------------------------------------------------------------------------
// 256x256-tile pipelined GEMM core v3: 8 waves (512 thr), BK=32, 4 LDS
// buffers (128 KiB), ONE barrier per K-tile. STAGE(t+2) is issued between
// the two 16-MFMA halves of COMP(t) (buffer (t+2)&3 collides with nothing
// live during iter t: readers use t&3, in-flight writes are (t+1)&3).
// vmcnt(4) at iter end drains tile t+1's loads, keeps t+2's in flight —
// never 0 until the tail. No setprio (null-to-negative on lockstep GEMM).
// ---------------------------------------------------------------------------
__device__ __forceinline__ void gemm_core256p(
    const short* __restrict__ A, const short* __restrict__ Wt,
    int mbase, int nbase, short* Asm, short* Bsm, floatx4 (&acc)[8][4])
{
    const int tid = threadIdx.x;
    const int lane = tid & 63, wid = tid >> 6;
    const int L15 = lane & 15, g = lane >> 4;
    const int wrow = (wid >> 2) * 128, wcol = (wid & 3) * 64;

    const int rl4 = lane >> 2, c4 = lane & 3;
    const int R0 = wid * 32;
    const short* aG = A  + (size_t)(mbase + R0 + rl4) * 1024 + c4 * 8;
    const short* bG = Wt + (size_t)(nbase + R0 + rl4) * 1024 + c4 * 8;

#define STAGE(t_) do {                                                        \
        const int sl_ = (t_) & 3;                                             \
        glds16(aG + (size_t)(t_) * 32,         Asm + sl_ * 8192 + R0 * 32);   \
        glds16(aG + (size_t)(t_) * 32 + 16384, Asm + sl_ * 8192 + R0 * 32 + 512); \
        glds16(bG + (size_t)(t_) * 32,         Bsm + sl_ * 8192 + R0 * 32);   \
        glds16(bG + (size_t)(t_) * 32 + 16384, Bsm + sl_ * 8192 + R0 * 32 + 512); \
    } while (0)

#define BARRIER_SB() do {                                                     \
        __builtin_amdgcn_sched_barrier(0);                                    \
        __builtin_amdgcn_s_barrier();                                         \
        __builtin_amdgcn_sched_barrier(0);                                    \
    } while (0)

    // prologue: stage tiles 0,1 (8 loads/thread in flight), wait tile 0
    STAGE(0); STAGE(1);
    asm volatile("s_waitcnt vmcnt(4)" ::: "memory");
    BARRIER_SB();

    for (int t = 0; t < 32; ++t) {
        const int sl = t & 3;
        const short* Ab = Asm + sl * 8192;
        const short* Bb = Bsm + sl * 8192;
        short8 bf[4], af[4];
        #pragma unroll
        for (int nt = 0; nt < 4; ++nt)
            bf[nt] = *reinterpret_cast<const short8*>(Bb + (wcol + nt * 16 + L15) * 32 + g * 8);
        #pragma unroll
        for (int mt = 0; mt < 4; ++mt)
            af[mt] = *reinterpret_cast<const short8*>(Ab + (wrow + mt * 16 + L15) * 32 + g * 8);
        #pragma unroll
        for (int mt = 0; mt < 4; ++mt)
            #pragma unroll
            for (int nt = 0; nt < 4; ++nt)
                acc[mt][nt] = mfma16(af[mt], bf[nt], acc[mt][nt]);

        if (t + 2 < 32) STAGE(t + 2);   // hidden under MFMA + ds_read

        #pragma unroll
        for (int mt = 0; mt < 4; ++mt)
            af[mt] = *reinterpret_cast<const short8*>(Ab + (wrow + 64 + mt * 16 + L15) * 32 + g * 8);
        #pragma unroll
        for (int mt = 0; mt < 4; ++mt)
            #pragma unroll
            for (int nt = 0; nt < 4; ++nt)
                acc[mt + 4][nt] = mfma16(af[mt], bf[nt], acc[mt + 4][nt]);

        if (t + 2 < 32)      asm volatile("s_waitcnt vmcnt(4)" ::: "memory");
        else if (t + 1 < 32) asm volatile("s_waitcnt vmcnt(0)" ::: "memory");
        BARRIER_SB();
    }

#undef STAGE
#undef BARRIER_SB
}

// ---------------------------------------------------------------------------
// 128x128-tile GEMM core (kept for out_gemm).
// ---------------------------------------------------------------------------
__device__ __forceinline__ void gemm_core(
    const short* __restrict__ A, const short* __restrict__ Wt,
    int mbase, int nbase, short* Asm, short* Bsm, floatx4 (&acc)[4][4])
{
    const int tid = threadIdx.x;
    const int lane = tid & 63, wid = tid >> 6;
    const int L15 = lane & 15, g = lane >> 4;
    const int wm = (wid >> 1) * 64, wn = (wid & 1) * 64;

    const int rowoff = lane >> 3;
    const int choff = ((lane & 7) ^ rowoff) * 8;
    const short* aP = A  + (size_t)(mbase + wid * 32 + rowoff) * 1024 + choff;
    const short* bP = Wt + (size_t)(nbase + wid * 32 + rowoff) * 1024 + choff;
    short* aL = Asm + wid * 2048;
    short* bL = Bsm + wid * 2048;

    const int xb = L15 & 7;
    const int s0 = (g ^ xb) * 8;
    const int s1 = ((g ^ 4) ^ xb) * 8;

    for (int kb = 0; kb < 1024; kb += 64) {
        __syncthreads();
        #pragma unroll
        for (int j = 0; j < 4; ++j) glds16(aP + kb + j * 8192, aL + j * 512);
        #pragma unroll
        for (int j = 0; j < 4; ++j) glds16(bP + kb + j * 8192, bL + j * 512);
        __syncthreads();
        #pragma unroll
        for (int ks = 0; ks < 2; ++ks) {
            const int so = ks ? s1 : s0;
            short8 af[4], bf[4];
            #pragma unroll
            for (int mt = 0; mt < 4; ++mt)
                af[mt] = *reinterpret_cast<const short8*>(Asm + (wm + mt * 16 + L15) * 64 + so);
            #pragma unroll
            for (int nt = 0; nt < 4; ++nt)
                bf[nt] = *reinterpret_cast<const short8*>(Bsm + (wn + nt * 16 + L15) * 64 + so);
            #pragma unroll
            for (int mt = 0; mt < 4; ++mt)
                #pragma unroll
                for (int nt = 0; nt < 4; ++nt)
                    acc[mt][nt] = mfma16(af[mt], bf[nt], acc[mt][nt]);
        }
    }
}

// ---------------------------------------------------------------------------
// Fused Q/K/V/G projections, 256^2 tiles, 512 threads, XCD chunk swizzle.
// Q written pre-scaled by 0.125*LOG2E. V^T pair-permuted, scalar RNE stores.
// ---------------------------------------------------------------------------
__global__ __launch_bounds__(512) void qkvg_gemm(
    const short* __restrict__ A, const short* __restrict__ Wt5,
    const float* __restrict__ b0, const float* __restrict__ b1,
    const float* __restrict__ b2, const float* __restrict__ b3,
    short* __restrict__ dQ, short* __restrict__ dK,
    short* __restrict__ dV, short* __restrict__ dG)
{
    __shared__ short Asm[4 * 8192];
    __shared__ short Bsm[4 * 8192];

    const int wg = blockIdx.x;
    const int swz = (wg & 7) * 32 + (wg >> 3);
    const int z = swz >> 6;
    const int rem = swz & 63;
    const int mbase = (rem >> 2) * 256, nbase = (rem & 3) * 256;

    floatx4 acc[8][4] = {};
    gemm_core256p(A, Wt5 + (size_t)z * 1048576, mbase, nbase, Asm, Bsm, acc);

    const int lane = threadIdx.x & 63, wid = threadIdx.x >> 6;
    const int L15 = lane & 15, g = lane >> 4;
    const int wrow = (wid >> 2) * 128, wcol = (wid & 3) * 64;
    const float* bz = (z == 0) ? b0 : (z == 1) ? b1 : (z == 2) ? b2 : b3;
    short* dst = (z == 0) ? dQ : (z == 1) ? dK : (z == 2) ? dV : dG;

    float bvv[4];
    #pragma unroll
    for (int nt = 0; nt < 4; ++nt) bvv[nt] = bz[nbase + wcol + nt * 16 + L15];

    if (z <= 1) {
        const float qsc = (z == 0) ? 0.125f * LOG2E : 1.0f;
        #pragma unroll
        for (int mt = 0; mt < 8; ++mt) {
            #pragma unroll
            for (int r = 0; r < 4; ++r) {
                int row = mbase + wrow + mt * 16 + g * 4 + r;
                int bb = row >> 11, s = row & 2047;
                #pragma unroll
                for (int nt = 0; nt < 4; ++nt) {
                    int col = nbase + wcol + nt * 16 + L15;
                    int hh = col >> 6, dh = col & 63;
                    dst[(((size_t)bb * 16 + hh) * 2048 + s) * 64 + dh] =
                        f2bf((acc[mt][nt][r] + bvv[nt]) * qsc);
                }
            }
        }
    } else if (z == 2) {
        #pragma unroll
        for (int nt = 0; nt < 4; ++nt) {
            int col = nbase + wcol + nt * 16 + L15;
            int hh = col >> 6, dh = col & 63;
            #pragma unroll
            for (int mt = 0; mt < 8; ++mt) {
                #pragma unroll
                for (int r = 0; r < 4; ++r) {
                    int row = mbase + wrow + mt * 16 + g * 4 + r;
                    int bb = row >> 11, s = row & 2047;
                    int sp = (s & ~31) | ((s & 15) << 1) | ((s >> 4) & 1);
                    dst[(((size_t)bb * 16 + hh) * 64 + dh) * 2048 + sp] =
                        f2bf(acc[mt][nt][r] + bvv[nt]);
                }
            }
        }
    } else {
        #pragma unroll
        for (int mt = 0; mt < 8; ++mt) {
            #pragma unroll
            for (int r = 0; r < 4; ++r) {
                int row = mbase + wrow + mt * 16 + g * 4 + r;
                #pragma unroll
                for (int nt = 0; nt < 4; ++nt) {
                    int col = nbase + wcol + nt * 16 + L15;
                    float e = fexp2(-(acc[mt][nt][r] + bvv[nt]) * LOG2E);
                    dst[(size_t)row * 1024 + col] = f2bf(__builtin_amdgcn_rcpf(1.0f + e));
                }
            }
        }
    }
}

// ---------------------------------------------------------------------------
__global__ __launch_bounds__(256) void out_gemm(
    const short* __restrict__ A, const short* __restrict__ Wt,
    const float* __restrict__ bias, float* __restrict__ out)
{
    __shared__ short Asm[128 * 64];
    __shared__ short Bsm[128 * 64];
    const int mbase = blockIdx.y * 128, nbase = blockIdx.x * 128;
    floatx4 acc[4][4] = {};
    gemm_core(A, Wt, mbase, nbase, Asm, Bsm, acc);

    const int lane = threadIdx.x & 63, wid = threadIdx.x >> 6;
    const int L15 = lane & 15, g = lane >> 4;
    const int wm = (wid >> 1) * 64, wn = (wid & 1) * 64;
    #pragma unroll
    for (int nt = 0; nt < 4; ++nt) {
        int col = nbase + wn + nt * 16 + L15;
        float bv = bias[col];
        #pragma unroll
        for (int mt = 0; mt < 4; ++mt)
            #pragma unroll
            for (int r = 0; r < 4; ++r) {
                int row = mbase + wm + mt * 16 + g * 4 + r;
                out[(size_t)row * 1024 + col] = acc[mt][nt][r] + bv;
            }
    }
}

// ---------------------------------------------------------------------------
// Flash attention: 512 threads, 8 waves x 16 q-rows, KVBLK=64, Q pre-scaled
// (scores arrive in log2 units), perm-packed P, zero-mask fast path.
// ---------------------------------------------------------------------------
template<bool MASKED>
__device__ __forceinline__ void flash_body(
    const short* __restrict__ Q, const short* __restrict__ K,
    const short* __restrict__ Vt, const short* __restrict__ G,
    const float* __restrict__ Mc, short* __restrict__ att,
    float* __restrict__ inv_l,
    short* Ksm, short* Vsm, short* Psm)
{
    const int tid = threadIdx.x;
    const int lane = tid & 63, wid = tid >> 6;
    const int L15 = lane & 15, g = lane >> 4;
    const int b = blockIdx.z, h = blockIdx.x;
    const int bh = b * 16 + h;
    const int qb = blockIdx.y * 128 + wid * 16;

    short8 aq0 = *reinterpret_cast<const short8*>(Q + ((size_t)bh * 2048 + qb + L15) * 64 + g * 8);
    short8 aq1 = *reinterpret_cast<const short8*>(Q + ((size_t)bh * 2048 + qb + L15) * 64 + 32 + g * 8);

    floatx4 O[4] = {};
    float l_r[4] = {0.f, 0.f, 0.f, 0.f};

    const int krow = lane >> 3;
    const int kch  = ((lane & 7) ^ krow) * 8;
    const bool isK = wid < 4;
    const int sw = isK ? wid : (wid - 4);
    const short* gP;
    if (isK) {
        gP = K + ((size_t)bh * 2048 + sw * 16 + krow) * 64 + kch;
    } else {
        const int vsc = (lane & 7) ^ krow;
        const int vhd = sw * 16 + 2 * krow + (vsc >> 2);
        gP = Vt + ((size_t)bh * 64 + vhd) * 2048 + (vsc & 3) * 8;
    }

    const int x7 = L15 & 7;
    const int sk0 = (g ^ x7) * 8, sk1 = ((g ^ 4) ^ x7) * 8;
    const int sv = (((L15 & 1) * 4 + g) ^ ((L15 >> 1) & 7)) * 8;
    const int vp = (L15 >> 1) * 64;

    short* Pw = Psm + wid * 1152;   // 16 rows x 72 shorts

    const float* mcP[4];
    float2 mc0[4], mc1[4];
    if (MASKED) {
        #pragma unroll
        for (int r = 0; r < 4; ++r) {
            mcP[r] = Mc + ((size_t)b * 2048 + qb + g * 4 + r) * 2048 + 2 * L15;
            mc0[r] = *reinterpret_cast<const float2*>(mcP[r]);
            mc1[r] = *reinterpret_cast<const float2*>(mcP[r] + 32);
        }
    }

    if (isK) {
        glds16(gP,       Ksm + sw * 1024);
        glds16(gP + 512, Ksm + sw * 1024 + 512);
    } else {
        glds16(gP,      Vsm + sw * 512);
        glds16(gP + 32, Vsm + 2048 + sw * 512);
    }

    for (int kb = 0; kb < 2048; kb += 64) {
        const int cur = (kb >> 6) & 1;
        __syncthreads();
        const int nb = kb + 64;
        const bool more = nb < 2048;
        float2 nmc0[4], nmc1[4];
        if (more) {
            if (isK) {
                glds16(gP + (size_t)nb * 64,       Ksm + (cur ^ 1) * 4096 + sw * 1024);
                glds16(gP + (size_t)nb * 64 + 512, Ksm + (cur ^ 1) * 4096 + sw * 1024 + 512);
            } else {
                glds16(gP + nb,      Vsm + (cur ^ 1) * 4096 + sw * 512);
                glds16(gP + nb + 32, Vsm + (cur ^ 1) * 4096 + 2048 + sw * 512);
            }
            if (MASKED) {
                #pragma unroll
                for (int r = 0; r < 4; ++r) {
                    nmc0[r] = *reinterpret_cast<const float2*>(mcP[r] + nb);
                    nmc1[r] = *reinterpret_cast<const float2*>(mcP[r] + nb + 32);
                }
            }
        }

        const short* Kb = Ksm + cur * 4096;
        floatx4 s[4];
        #pragma unroll
        for (int kt = 0; kt < 4; ++kt) {
            s[kt] = {};
            s[kt] = mfma16(aq0, *reinterpret_cast<const short8*>(Kb + (kt * 16 + L15) * 64 + sk0), s[kt]);
            s[kt] = mfma16(aq1, *reinterpret_cast<const short8*>(Kb + (kt * 16 + L15) * 64 + sk1), s[kt]);
        }

        #pragma unroll
        for (int r = 0; r < 4; ++r) {
            float e0 = fexp2(MASKED ? s[0][r] + mc0[r].x : s[0][r]);
            float e1 = fexp2(MASKED ? s[1][r] + mc0[r].y : s[1][r]);
            float e2 = fexp2(MASKED ? s[2][r] + mc1[r].x : s[2][r]);
            float e3 = fexp2(MASKED ? s[3][r] + mc1[r].y : s[3][r]);
            l_r[r] += (e0 + e1) + (e2 + e3);
            *reinterpret_cast<unsigned*>(&Pw[(g * 4 + r) * 72 + 2 * L15])      = bfpack(e0, e1);
            *reinterpret_cast<unsigned*>(&Pw[(g * 4 + r) * 72 + 32 + 2 * L15]) = bfpack(e2, e3);
        }
        short8 ap0 = *reinterpret_cast<const short8*>(&Pw[L15 * 72 + g * 8]);
        short8 ap1 = *reinterpret_cast<const short8*>(&Pw[L15 * 72 + 32 + g * 8]);
        const short* Vb0 = Vsm + cur * 4096;
        const short* Vb1 = Vb0 + 2048;
        #pragma unroll
        for (int t = 0; t < 4; ++t) {
            O[t] = mfma16(ap0, *reinterpret_cast<const short8*>(Vb0 + t * 512 + vp + sv), O[t]);
            O[t] = mfma16(ap1, *reinterpret_cast<const short8*>(Vb1 + t * 512 + vp + sv), O[t]);
        }

        if (MASKED && more) {
            #pragma unroll
            for (int r = 0; r < 4; ++r) { mc0[r] = nmc0[r]; mc1[r] = nmc1[r]; }
        }
    }

    float inv[4];
    #pragma unroll
    for (int r = 0; r < 4; ++r) {
        float ls = l_r[r];
        ls += __shfl_xor(ls, 1);
        ls += __shfl_xor(ls, 2);
        ls += __shfl_xor(ls, 4);
        ls += __shfl_xor(ls, 8);
        inv[r] = 1.0f / ls;
        if (L15 == 0) inv_l[(size_t)bh * 2048 + qb + g * 4 + r] = inv[r];
    }
    #pragma unroll
    for (int t = 0; t < 4; ++t) {
        int col = h * 64 + t * 16 + L15;
        #pragma unroll
        for (int r = 0; r < 4; ++r) {
            size_t qr = qb + g * 4 + r;
            float gt = bf2f(G[((size_t)b * 2048 + qr) * 1024 + col]);
            att[((size_t)b * 2048 + qr) * 1024 + col] = f2bf(O[t][r] * inv[r] * gt);
        }
    }
}

__global__ __launch_bounds__(512, 4) void flash_attn(
    const short* __restrict__ Q, const short* __restrict__ K,
    const short* __restrict__ Vt, const short* __restrict__ G,
    const float* __restrict__ Mc, const int* __restrict__ flag,
    short* __restrict__ att, float* __restrict__ inv_l)
{
    __shared__ short Ksm[2 * 4096];
    __shared__ short Vsm[2 * 4096];
    __shared__ short Psm[8 * 1152];
    if (*flag)
        flash_body<true>(Q, K, Vt, G, Mc, att, inv_l, Ksm, Vsm, Psm);
    else
        flash_body<false>(Q, K, Vt, G, Mc, att, inv_l, Ksm, Vsm, Psm);
}

// ---------------------------------------------------------------------------
// avg_attn body, templated on MASKED (unmasked path = bare exp2, no pm).
// ---------------------------------------------------------------------------
template<bool MASKED>
__device__ __forceinline__ void avg_body(
    const short* __restrict__ Q, const short* __restrict__ K,
    const float* __restrict__ inv_l, float* mca, short* KsmBase)
{
    const int tid = threadIdx.x;
    const int lane = tid & 63, wid = tid >> 6;
    const int L15 = lane & 15, g = lane >> 4;
    const int b = blockIdx.z;
    const int qb = blockIdx.y * 64 + wid * 16;
    const int ks = blockIdx.x * 128;

    float pm[4][2][4];
    if (MASKED) {
        #pragma unroll
        for (int c = 0; c < 4; ++c)
            #pragma unroll
            for (int r = 0; r < 4; ++r) {
                size_t qr = qb + g * 4 + r;
                float2 m = *reinterpret_cast<const float2*>(
                    mca + ((size_t)b * 2048 + qr) * 2048 + ks + c * 32 + 2 * L15);
                pm[c][0][r] = m.x;
                pm[c][1][r] = m.y;
            }
    }
    float av[4][2][4] = {};

    const int rowoff = lane >> 3;
    const int choff = ((lane & 7) ^ rowoff) * 8;
    const int x7 = L15 & 7;
    const int sk0 = (g ^ x7) * 8, sk1 = ((g ^ 4) ^ x7) * 8;
    short* kL[2] = { KsmBase + wid * 2048, KsmBase + 8192 + wid * 2048 };

    {
        const short* p = K + ((size_t)(b * 16) * 2048 + ks + wid * 32 + rowoff) * 64 + choff;
        #pragma unroll
        for (int j = 0; j < 4; ++j) glds16(p + j * 512, kL[0] + j * 512);
    }
    short8 aq0 = *reinterpret_cast<const short8*>(Q + ((size_t)(b * 16) * 2048 + qb + L15) * 64 + g * 8);
    short8 aq1 = *reinterpret_cast<const short8*>(Q + ((size_t)(b * 16) * 2048 + qb + L15) * 64 + 32 + g * 8);
    float iv[4];
    #pragma unroll
    for (int r = 0; r < 4; ++r) iv[r] = inv_l[(size_t)(b * 16) * 2048 + qb + g * 4 + r];

    for (int h = 0; h < 16; ++h) {
        __syncthreads();
        short8 naq0, naq1;
        float niv[4];
        if (h < 15) {
            int nbh = b * 16 + h + 1;
            const short* p = K + ((size_t)nbh * 2048 + ks + wid * 32 + rowoff) * 64 + choff;
            #pragma unroll
            for (int j = 0; j < 4; ++j) glds16(p + j * 512, kL[(h + 1) & 1] + j * 512);
            naq0 = *reinterpret_cast<const short8*>(Q + ((size_t)nbh * 2048 + qb + L15) * 64 + g * 8);
            naq1 = *reinterpret_cast<const short8*>(Q + ((size_t)nbh * 2048 + qb + L15) * 64 + 32 + g * 8);
            #pragma unroll
            for (int r = 0; r < 4; ++r) niv[r] = inv_l[(size_t)nbh * 2048 + qb + g * 4 + r];
        }

        const short* Kb = KsmBase + (h & 1) * 8192;
        #pragma unroll
        for (int c = 0; c < 4; ++c) {
            const short* kbase = Kb + c * 32 * 64;
            floatx4 s0 = {}, s1 = {};
            s0 = mfma16(aq0, *reinterpret_cast<const short8*>(kbase + L15 * 64 + sk0), s0);
            s0 = mfma16(aq1, *reinterpret_cast<const short8*>(kbase + L15 * 64 + sk1), s0);
            s1 = mfma16(aq0, *reinterpret_cast<const short8*>(kbase + (16 + L15) * 64 + sk0), s1);
            s1 = mfma16(aq1, *reinterpret_cast<const short8*>(kbase + (16 + L15) * 64 + sk1), s1);
            #pragma unroll
            for (int r = 0; r < 4; ++r) {
                av[c][0][r] += fexp2(MASKED ? s0[r] + pm[c][0][r] : s0[r]) * iv[r];
                av[c][1][r] += fexp2(MASKED ? s1[r] + pm[c][1][r] : s1[r]) * iv[r];
            }
        }
        if (h < 15) {
            aq0 = naq0; aq1 = naq1;
            #pragma unroll
            for (int r = 0; r < 4; ++r) iv[r] = niv[r];
        }
    }
    #pragma unroll
    for (int c = 0; c < 4; ++c)
        #pragma unroll
        for (int t = 0; t < 2; ++t)
            #pragma unroll
            for (int r = 0; r < 4; ++r) {
                size_t qr = qb + g * 4 + r;
                int col = ks + c * 32 + t * 16 + L15;
                mca[((size_t)b * 2048 + qr) * 2048 + col] = av[c][t][r] * 0.0625f;
            }
}

__global__ __launch_bounds__(256) void avg_attn_kernel(
    const short* __restrict__ Q, const short* __restrict__ K,
    const float* __restrict__ inv_l, float* mca, const int* __restrict__ flag)
{
    __shared__ short Ksm[2 * 128 * 64];
    if (*flag)
        avg_body<true>(Q, K, inv_l, mca, Ksm);
    else
        avg_body<false>(Q, K, inv_l, mca, Ksm);
}

// ---------------------------------------------------------------------------
extern "C" void kernel_launch(void* const* d_in, const int* in_sizes, int n_in,
                              void* d_out, int out_size, void* d_ws, size_t ws_size,
                              hipStream_t stream)
{
    const float* x  = (const float*)d_in[0];
    const float* amask = (const float*)d_in[1];
    const unsigned char* kpm = (const unsigned char*)d_in[2];
    const float* Wq = (const float*)d_in[3];
    const float* bq = (const float*)d_in[4];
    const float* Wk = (const float*)d_in[5];
    const float* bk = (const float*)d_in[6];
    const float* Wv = (const float*)d_in[7];
    const float* bv = (const float*)d_in[8];
    const float* Wg = (const float*)d_in[9];
    const float* bg = (const float*)d_in[10];
    const float* Wo = (const float*)d_in[11];
    const float* bo = (const float*)d_in[12];

    char* ws = (char*)d_ws;
    const size_t MB = 1u << 20;
    short* Xb    = (short*)(ws);                 // 8 MB bf16 x (reused as Att)
    short* Att   = Xb;
    short* Qw    = (short*)(ws + 8 * MB);        // [bh][2048][64] (pre-scaled)
    short* Kw    = (short*)(ws + 16 * MB);       // [bh][2048][64]
    short* Vt    = (short*)(ws + 24 * MB);       // [bh][64][2048] (key-permuted)
    short* Gw    = (short*)(ws + 32 * MB);       // bf16 gate [m][1024]
    short* Wt    = (short*)(ws + 40 * MB);       // 5 x [1024n][1024k] bf16
    float* stats = (float*)(ws + 50 * MB);       // inv_l (256 KB)
    int*   flagp = (int*)(ws + 50 * MB + 262144);

    float* outp = (float*)d_out;                 // [2][2048][1024]
    float* avgp = (float*)d_out + 4194304;       // [2][2048][2048]; holds Mc first

    hipMemsetAsync(flagp, 0, sizeof(int), stream);

    flag_scan<<<2048, 256, 0, stream>>>(amask, kpm, flagp);

    cvt_x_kernel<<<2048, 256, 0, stream>>>(x, Xb, 524288);
    cvt_wt_kernel<<<dim3(16, 16, 5), 256, 0, stream>>>(Wq, Wk, Wv, Wg, Wo, Wt);
    mask_prep<<<dim3(1, 2048, 2), 256, 0, stream>>>(amask, kpm, avgp, flagp);

    qkvg_gemm<<<256, 512, 0, stream>>>(Xb, Wt, bq, bk, bv, bg, Qw, Kw, Vt, Gw);

    flash_attn<<<dim3(16, 16, 2), 512, 0, stream>>>(Qw, Kw, Vt, Gw, avgp, flagp, Att, stats);

    avg_attn_kernel<<<dim3(16, 32, 2), 256, 0, stream>>>(Qw, Kw, stats, avgp, flagp);

    out_gemm<<<dim3(8, 32), 256, 0, stream>>>(Att, Wt + 4 * 1048576, bo, outp);
}

// Round 8
// 266.098 us; speedup vs baseline: 1.0618x; 1.0117x over previous
//
#include <hip/hip_runtime.h>
#include <hip/hip_bf16.h>

#define LOG2E 1.4426950408889634f

typedef short short8 __attribute__((ext_vector_type(8)));
typedef float floatx4 __attribute__((ext_vector_type(4)));

__device__ __forceinline__ floatx4 mfma16(short8 a, short8 b, floatx4 c) {
    return __builtin_amdgcn_mfma_f32_16x16x32_bf16(a, b, c, 0, 0, 0);
}

__device__ __forceinline__ float fexp2(float x) { return __builtin_amdgcn_exp2f(x); }

// fast RNE fp32->bf16 (finite inputs only)
__device__ __forceinline__ short f2bf(float f) {
    unsigned u = __builtin_bit_cast(unsigned, f);
    u += 0x7FFFu + ((u >> 16) & 1u);
    return (short)(u >> 16);
}
// pack two fp32 -> (bf16(a) | bf16(b)<<16), round-half-up (+0x8000) + byte
// perm. Differs from RNE only on exact ties (low16==0x8000, p~2^-16),
// unbiased unlike v_cvt_pk_bf16_f32 (RTZ — broke the absmax gate in R4).
__device__ __forceinline__ unsigned bfpack(float a, float b) {
    unsigned ua = __builtin_bit_cast(unsigned, a) + 0x8000u;
    unsigned ub = __builtin_bit_cast(unsigned, b) + 0x8000u;
    return __builtin_amdgcn_perm(ub, ua, 0x07060302u);
}
__device__ __forceinline__ float bf2f(short s) {
    unsigned u = ((unsigned)(unsigned short)s) << 16;
    return __builtin_bit_cast(float, u);
}

// async global->LDS, 16B per lane
__device__ __forceinline__ void glds16(const void* g, void* l) {
    __builtin_amdgcn_global_load_lds(
        (const __attribute__((address_space(1))) void*)g,
        (__attribute__((address_space(3))) void*)l, 16, 0, 0);
}

__device__ __forceinline__ short8 cvt8(const float* __restrict__ p) {
    float4 a = *reinterpret_cast<const float4*>(p);
    float4 b = *reinterpret_cast<const float4*>(p + 4);
    short8 r;
    r[0] = f2bf(a.x); r[1] = f2bf(a.y); r[2] = f2bf(a.z); r[3] = f2bf(a.w);
    r[4] = f2bf(b.x); r[5] = f2bf(b.y); r[6] = f2bf(b.z); r[7] = f2bf(b.w);
    return r;
}

// ---------------------------------------------------------------------------
__global__ __launch_bounds__(256) void cvt_x_kernel(
    const float* __restrict__ in, short* __restrict__ out, int n8)
{
    int i = blockIdx.x * blockDim.x + threadIdx.x;
    if (i < n8)
        *reinterpret_cast<short8*>(out + (size_t)i * 8) = cvt8(in + (size_t)i * 8);
}

// ---------------------------------------------------------------------------
__global__ __launch_bounds__(256) void cvt_wt_kernel(
    const float* __restrict__ W0, const float* __restrict__ W1,
    const float* __restrict__ W2, const float* __restrict__ W3,
    const float* __restrict__ W4, short* __restrict__ Wt)
{
    __shared__ short T[64 * 66];
    const int w = blockIdx.z;
    const float* W = (w == 0) ? W0 : (w == 1) ? W1 : (w == 2) ? W2 : (w == 3) ? W3 : W4;
    short* dst = Wt + (size_t)w * 1024 * 1024;
    const int kb = blockIdx.y * 64, nb = blockIdx.x * 64;
    const int t = threadIdx.x;
    const int r = t >> 2, c4 = (t & 3) * 16;
    *reinterpret_cast<short8*>(T + r * 66 + c4)     = cvt8(W + (size_t)(kb + r) * 1024 + nb + c4);
    *reinterpret_cast<short8*>(T + r * 66 + c4 + 8) = cvt8(W + (size_t)(kb + r) * 1024 + nb + c4 + 8);
    __syncthreads();
    short8 o0, o1;
    #pragma unroll
    for (int j = 0; j < 8; ++j) o0[j] = T[(c4 + j) * 66 + r];
    #pragma unroll
    for (int j = 0; j < 8; ++j) o1[j] = T[(c4 + 8 + j) * 66 + r];
    *reinterpret_cast<short8*>(dst + (size_t)(nb + r) * 1024 + kb + c4)     = o0;
    *reinterpret_cast<short8*>(dst + (size_t)(nb + r) * 1024 + kb + c4 + 8) = o1;
}

// ---------------------------------------------------------------------------
// flag_scan: any-nonzero over amask + kpm -> *flag.
// ---------------------------------------------------------------------------
__global__ __launch_bounds__(256) void flag_scan(
    const float* __restrict__ amask, const unsigned char* __restrict__ kpm,
    int* __restrict__ flag)
{
    const int i = blockIdx.x * 256 + threadIdx.x;
    const float4* a4 = reinterpret_cast<const float4*>(amask);
    float4 v0 = a4[(size_t)i * 2];
    float4 v1 = a4[(size_t)i * 2 + 1];
    bool nz = (v0.x != 0.f) | (v0.y != 0.f) | (v0.z != 0.f) | (v0.w != 0.f)
            | (v1.x != 0.f) | (v1.y != 0.f) | (v1.z != 0.f) | (v1.w != 0.f);
    if (blockIdx.x == 0) {
        const uint4* k4 = reinterpret_cast<const uint4*>(kpm);
        uint4 kv = k4[threadIdx.x];
        nz |= ((kv.x | kv.y | kv.z | kv.w) != 0u);
    }
    if (__ballot(nz) && ((threadIdx.x & 63) == 0)) atomicOr(flag, 1);
}

// ---------------------------------------------------------------------------
// mask prepass (masked path only). Early-exits when flag==0.
// ---------------------------------------------------------------------------
__global__ __launch_bounds__(256) void mask_prep(
    const float* __restrict__ amask, const unsigned char* __restrict__ kpm,
    float* __restrict__ Mc, const int* __restrict__ flag)
{
    if (*flag == 0) return;
    const int b = blockIdx.z, q = blockIdx.y;
    const int p0 = threadIdx.x * 8;
    float o[8];
    #pragma unroll
    for (int i = 0; i < 8; ++i) {
        int p = p0 + i;
        int j = (p & ~31) | ((p >> 1) & 15) | ((p & 1) << 4);
        unsigned char kb = kpm[b * 2048 + j];
        float a = amask[(size_t)q * 2048 + j];
        o[i] = a * LOG2E + (kb ? -1.0e30f : 0.f);
    }
    float* dst = Mc + ((size_t)b * 2048 + q) * 2048 + p0;
    *reinterpret_cast<float4*>(dst)     = make_float4(o[0], o[1], o[2], o[3]);
    *reinterpret_cast<float4*>(dst + 4) = make_float4(o[4], o[5], o[6], o[7]);
}

// ---------------------------------------------------------------------------
// 256x256-tile pipelined GEMM core v3: 8 waves (512 thr), BK=32, 4 LDS
// buffers (128 KiB), ONE barrier per K-tile; STAGE(t+2) hidden inside the
// MFMA body; counted vmcnt(4) (never 0 until tail).
// ---------------------------------------------------------------------------
__device__ __forceinline__ void gemm_core256p(
    const short* __restrict__ A, const short* __restrict__ Wt,
    int mbase, int nbase, short* Asm, short* Bsm, floatx4 (&acc)[8][4])
{
    const int tid = threadIdx.x;
    const int lane = tid & 63, wid = tid >> 6;
    const int L15 = lane & 15, g = lane >> 4;
    const int wrow = (wid >> 2) * 128, wcol = (wid & 3) * 64;

    const int rl4 = lane >> 2, c4 = lane & 3;
    const int R0 = wid * 32;
    const short* aG = A  + (size_t)(mbase + R0 + rl4) * 1024 + c4 * 8;
    const short* bG = Wt + (size_t)(nbase + R0 + rl4) * 1024 + c4 * 8;

#define STAGE(t_) do {                                                        \
        const int sl_ = (t_) & 3;                                             \
        glds16(aG + (size_t)(t_) * 32,         Asm + sl_ * 8192 + R0 * 32);   \
        glds16(aG + (size_t)(t_) * 32 + 16384, Asm + sl_ * 8192 + R0 * 32 + 512); \
        glds16(bG + (size_t)(t_) * 32,         Bsm + sl_ * 8192 + R0 * 32);   \
        glds16(bG + (size_t)(t_) * 32 + 16384, Bsm + sl_ * 8192 + R0 * 32 + 512); \
    } while (0)

#define BARRIER_SB() do {                                                     \
        __builtin_amdgcn_sched_barrier(0);                                    \
        __builtin_amdgcn_s_barrier();                                         \
        __builtin_amdgcn_sched_barrier(0);                                    \
    } while (0)

    STAGE(0); STAGE(1);
    asm volatile("s_waitcnt vmcnt(4)" ::: "memory");
    BARRIER_SB();

    for (int t = 0; t < 32; ++t) {
        const int sl = t & 3;
        const short* Ab = Asm + sl * 8192;
        const short* Bb = Bsm + sl * 8192;
        short8 bf[4], af[4];
        #pragma unroll
        for (int nt = 0; nt < 4; ++nt)
            bf[nt] = *reinterpret_cast<const short8*>(Bb + (wcol + nt * 16 + L15) * 32 + g * 8);
        #pragma unroll
        for (int mt = 0; mt < 4; ++mt)
            af[mt] = *reinterpret_cast<const short8*>(Ab + (wrow + mt * 16 + L15) * 32 + g * 8);
        #pragma unroll
        for (int mt = 0; mt < 4; ++mt)
            #pragma unroll
            for (int nt = 0; nt < 4; ++nt)
                acc[mt][nt] = mfma16(af[mt], bf[nt], acc[mt][nt]);

        if (t + 2 < 32) STAGE(t + 2);   // hidden under MFMA + ds_read

        #pragma unroll
        for (int mt = 0; mt < 4; ++mt)
            af[mt] = *reinterpret_cast<const short8*>(Ab + (wrow + 64 + mt * 16 + L15) * 32 + g * 8);
        #pragma unroll
        for (int mt = 0; mt < 4; ++mt)
            #pragma unroll
            for (int nt = 0; nt < 4; ++nt)
                acc[mt + 4][nt] = mfma16(af[mt], bf[nt], acc[mt + 4][nt]);

        if (t + 2 < 32)      asm volatile("s_waitcnt vmcnt(4)" ::: "memory");
        else if (t + 1 < 32) asm volatile("s_waitcnt vmcnt(0)" ::: "memory");
        BARRIER_SB();
    }

#undef STAGE
#undef BARRIER_SB
}

// ---------------------------------------------------------------------------
// 128x128-tile GEMM core (kept for out_gemm).
// ---------------------------------------------------------------------------
__device__ __forceinline__ void gemm_core(
    const short* __restrict__ A, const short* __restrict__ Wt,
    int mbase, int nbase, short* Asm, short* Bsm, floatx4 (&acc)[4][4])
{
    const int tid = threadIdx.x;
    const int lane = tid & 63, wid = tid >> 6;
    const int L15 = lane & 15, g = lane >> 4;
    const int wm = (wid >> 1) * 64, wn = (wid & 1) * 64;

    const int rowoff = lane >> 3;
    const int choff = ((lane & 7) ^ rowoff) * 8;
    const short* aP = A  + (size_t)(mbase + wid * 32 + rowoff) * 1024 + choff;
    const short* bP = Wt + (size_t)(nbase + wid * 32 + rowoff) * 1024 + choff;
    short* aL = Asm + wid * 2048;
    short* bL = Bsm + wid * 2048;

    const int xb = L15 & 7;
    const int s0 = (g ^ xb) * 8;
    const int s1 = ((g ^ 4) ^ xb) * 8;

    for (int kb = 0; kb < 1024; kb += 64) {
        __syncthreads();
        #pragma unroll
        for (int j = 0; j < 4; ++j) glds16(aP + kb + j * 8192, aL + j * 512);
        #pragma unroll
        for (int j = 0; j < 4; ++j) glds16(bP + kb + j * 8192, bL + j * 512);
        __syncthreads();
        #pragma unroll
        for (int ks = 0; ks < 2; ++ks) {
            const int so = ks ? s1 : s0;
            short8 af[4], bf[4];
            #pragma unroll
            for (int mt = 0; mt < 4; ++mt)
                af[mt] = *reinterpret_cast<const short8*>(Asm + (wm + mt * 16 + L15) * 64 + so);
            #pragma unroll
            for (int nt = 0; nt < 4; ++nt)
                bf[nt] = *reinterpret_cast<const short8*>(Bsm + (wn + nt * 16 + L15) * 64 + so);
            #pragma unroll
            for (int mt = 0; mt < 4; ++mt)
                #pragma unroll
                for (int nt = 0; nt < 4; ++nt)
                    acc[mt][nt] = mfma16(af[mt], bf[nt], acc[mt][nt]);
        }
    }
}

// ---------------------------------------------------------------------------
// Fused Q/K/V/G projections, 256^2 tiles, 512 threads, XCD chunk swizzle.
// Q written pre-scaled by 0.125*LOG2E. V^T pair-permuted, scalar RNE stores.
// ---------------------------------------------------------------------------
__global__ __launch_bounds__(512) void qkvg_gemm(
    const short* __restrict__ A, const short* __restrict__ Wt5,
    const float* __restrict__ b0, const float* __restrict__ b1,
    const float* __restrict__ b2, const float* __restrict__ b3,
    short* __restrict__ dQ, short* __restrict__ dK,
    short* __restrict__ dV, short* __restrict__ dG)
{
    __shared__ short Asm[4 * 8192];
    __shared__ short Bsm[4 * 8192];

    const int wg = blockIdx.x;
    const int swz = (wg & 7) * 32 + (wg >> 3);
    const int z = swz >> 6;
    const int rem = swz & 63;
    const int mbase = (rem >> 2) * 256, nbase = (rem & 3) * 256;

    floatx4 acc[8][4] = {};
    gemm_core256p(A, Wt5 + (size_t)z * 1048576, mbase, nbase, Asm, Bsm, acc);

    const int lane = threadIdx.x & 63, wid = threadIdx.x >> 6;
    const int L15 = lane & 15, g = lane >> 4;
    const int wrow = (wid >> 2) * 128, wcol = (wid & 3) * 64;
    const float* bz = (z == 0) ? b0 : (z == 1) ? b1 : (z == 2) ? b2 : b3;
    short* dst = (z == 0) ? dQ : (z == 1) ? dK : (z == 2) ? dV : dG;

    float bvv[4];
    #pragma unroll
    for (int nt = 0; nt < 4; ++nt) bvv[nt] = bz[nbase + wcol + nt * 16 + L15];

    if (z <= 1) {
        const float qsc = (z == 0) ? 0.125f * LOG2E : 1.0f;
        #pragma unroll
        for (int mt = 0; mt < 8; ++mt) {
            #pragma unroll
            for (int r = 0; r < 4; ++r) {
                int row = mbase + wrow + mt * 16 + g * 4 + r;
                int bb = row >> 11, s = row & 2047;
                #pragma unroll
                for (int nt = 0; nt < 4; ++nt) {
                    int col = nbase + wcol + nt * 16 + L15;
                    int hh = col >> 6, dh = col & 63;
                    dst[(((size_t)bb * 16 + hh) * 2048 + s) * 64 + dh] =
                        f2bf((acc[mt][nt][r] + bvv[nt]) * qsc);
                }
            }
        }
    } else if (z == 2) {
        #pragma unroll
        for (int nt = 0; nt < 4; ++nt) {
            int col = nbase + wcol + nt * 16 + L15;
            int hh = col >> 6, dh = col & 63;
            #pragma unroll
            for (int mt = 0; mt < 8; ++mt) {
                #pragma unroll
                for (int r = 0; r < 4; ++r) {
                    int row = mbase + wrow + mt * 16 + g * 4 + r;
                    int bb = row >> 11, s = row & 2047;
                    int sp = (s & ~31) | ((s & 15) << 1) | ((s >> 4) & 1);
                    dst[(((size_t)bb * 16 + hh) * 64 + dh) * 2048 + sp] =
                        f2bf(acc[mt][nt][r] + bvv[nt]);
                }
            }
        }
    } else {
        #pragma unroll
        for (int mt = 0; mt < 8; ++mt) {
            #pragma unroll
            for (int r = 0; r < 4; ++r) {
                int row = mbase + wrow + mt * 16 + g * 4 + r;
                #pragma unroll
                for (int nt = 0; nt < 4; ++nt) {
                    int col = nbase + wcol + nt * 16 + L15;
                    float e = fexp2(-(acc[mt][nt][r] + bvv[nt]) * LOG2E);
                    dst[(size_t)row * 1024 + col] = f2bf(__builtin_amdgcn_rcpf(1.0f + e));
                }
            }
        }
    }
}

// ---------------------------------------------------------------------------
__global__ __launch_bounds__(256) void out_gemm(
    const short* __restrict__ A, const short* __restrict__ Wt,
    const float* __restrict__ bias, float* __restrict__ out)
{
    __shared__ short Asm[128 * 64];
    __shared__ short Bsm[128 * 64];
    const int mbase = blockIdx.y * 128, nbase = blockIdx.x * 128;
    floatx4 acc[4][4] = {};
    gemm_core(A, Wt, mbase, nbase, Asm, Bsm, acc);

    const int lane = threadIdx.x & 63, wid = threadIdx.x >> 6;
    const int L15 = lane & 15, g = lane >> 4;
    const int wm = (wid >> 1) * 64, wn = (wid & 1) * 64;
    #pragma unroll
    for (int nt = 0; nt < 4; ++nt) {
        int col = nbase + wn + nt * 16 + L15;
        float bv = bias[col];
        #pragma unroll
        for (int mt = 0; mt < 4; ++mt)
            #pragma unroll
            for (int r = 0; r < 4; ++r) {
                int row = mbase + wm + mt * 16 + g * 4 + r;
                out[(size_t)row * 1024 + col] = acc[mt][nt][r] + bv;
            }
    }
}

// ---------------------------------------------------------------------------
// Flash attention v2: 256 threads, 4 waves x 32 q-rows (128 q/block),
// KVBLK=64. Each K/V fragment read from LDS feeds TWO q-groups (rows +0..15
// and +16..31), halving LDS fragment traffic per q-row (flash was
// LDS-throughput-bound: ~2100 cyc/tile LDS demand vs ~2010 wall).
// Staging: waves 0-1 stage K (4 glds), waves 2-3 stage V (4 glds).
// Arithmetic per q-row identical to R7 (same fragments, same order).
// ---------------------------------------------------------------------------
template<bool MASKED>
__device__ __forceinline__ void flash_body(
    const short* __restrict__ Q, const short* __restrict__ K,
    const short* __restrict__ Vt, const short* __restrict__ G,
    const float* __restrict__ Mc, short* __restrict__ att,
    float* __restrict__ inv_l,
    short* Ksm, short* Vsm, short* Psm)
{
    const int tid = threadIdx.x;
    const int lane = tid & 63, wid = tid >> 6;     // wid 0..3
    const int L15 = lane & 15, g = lane >> 4;
    const int b = blockIdx.z, h = blockIdx.x;
    const int bh = b * 16 + h;
    const int qb = blockIdx.y * 128 + wid * 32;    // wave's 32 q-rows

    short8 aq0a = *reinterpret_cast<const short8*>(Q + ((size_t)bh * 2048 + qb + L15) * 64 + g * 8);
    short8 aq1a = *reinterpret_cast<const short8*>(Q + ((size_t)bh * 2048 + qb + L15) * 64 + 32 + g * 8);
    short8 aq0b = *reinterpret_cast<const short8*>(Q + ((size_t)bh * 2048 + qb + 16 + L15) * 64 + g * 8);
    short8 aq1b = *reinterpret_cast<const short8*>(Q + ((size_t)bh * 2048 + qb + 16 + L15) * 64 + 32 + g * 8);

    floatx4 Oa[4] = {}, Ob[4] = {};
    float la[4] = {0.f, 0.f, 0.f, 0.f}, lb[4] = {0.f, 0.f, 0.f, 0.f};

    // staging: waves 0-1 -> K keys [sw*32..+31]; waves 2-3 -> V dims [sw*32..+31]
    const int krow = lane >> 3;
    const int kch  = ((lane & 7) ^ krow) * 8;
    const bool isK = wid < 2;
    const int sw = isK ? wid : (wid - 2);
    const short* gP;
    if (isK) {
        gP = K + ((size_t)bh * 2048 + sw * 32 + krow) * 64 + kch;
    } else {
        const int vsc = (lane & 7) ^ krow;
        const int vhd = sw * 32 + 2 * krow + (vsc >> 2);
        gP = Vt + ((size_t)bh * 64 + vhd) * 2048 + (vsc & 3) * 8;
    }

    const int x7 = L15 & 7;
    const int sk0 = (g ^ x7) * 8, sk1 = ((g ^ 4) ^ x7) * 8;
    const int sv = (((L15 & 1) * 4 + g) ^ ((L15 >> 1) & 7)) * 8;
    const int vp = (L15 >> 1) * 64;

    short* Pw = Psm + wid * 2304;   // 32 rows x 72 shorts per wave

    const float* mcPa[4];
    float2 mc0a[4], mc1a[4], mc0b[4], mc1b[4];
    if (MASKED) {
        #pragma unroll
        for (int r = 0; r < 4; ++r) {
            mcPa[r] = Mc + ((size_t)b * 2048 + qb + g * 4 + r) * 2048 + 2 * L15;
            mc0a[r] = *reinterpret_cast<const float2*>(mcPa[r]);
            mc1a[r] = *reinterpret_cast<const float2*>(mcPa[r] + 32);
            mc0b[r] = *reinterpret_cast<const float2*>(mcPa[r] + 16 * 2048);
            mc1b[r] = *reinterpret_cast<const float2*>(mcPa[r] + 16 * 2048 + 32);
        }
    }

    // prologue: stage buffer 0 (tile kb=0)
    if (isK) {
        #pragma unroll
        for (int j = 0; j < 4; ++j)
            glds16(gP + j * 512, Ksm + sw * 2048 + j * 512);
    } else {
        #pragma unroll
        for (int j = 0; j < 2; ++j) {
            glds16(gP + j * 32768,      Vsm + sw * 1024 + j * 512);
            glds16(gP + j * 32768 + 32, Vsm + 2048 + sw * 1024 + j * 512);
        }
    }

    for (int kb = 0; kb < 2048; kb += 64) {
        const int cur = (kb >> 6) & 1;
        __syncthreads();
        const int nb = kb + 64;
        const bool more = nb < 2048;
        float2 nmc0a[4], nmc1a[4], nmc0b[4], nmc1b[4];
        if (more) {
            const int nbuf = (cur ^ 1) * 4096;
            if (isK) {
                #pragma unroll
                for (int j = 0; j < 4; ++j)
                    glds16(gP + (size_t)nb * 64 + j * 512, Ksm + nbuf + sw * 2048 + j * 512);
            } else {
                #pragma unroll
                for (int j = 0; j < 2; ++j) {
                    glds16(gP + nb + j * 32768,      Vsm + nbuf + sw * 1024 + j * 512);
                    glds16(gP + nb + j * 32768 + 32, Vsm + nbuf + 2048 + sw * 1024 + j * 512);
                }
            }
            if (MASKED) {
                #pragma unroll
                for (int r = 0; r < 4; ++r) {
                    nmc0a[r] = *reinterpret_cast<const float2*>(mcPa[r] + nb);
                    nmc1a[r] = *reinterpret_cast<const float2*>(mcPa[r] + nb + 32);
                    nmc0b[r] = *reinterpret_cast<const float2*>(mcPa[r] + 16 * 2048 + nb);
                    nmc1b[r] = *reinterpret_cast<const float2*>(mcPa[r] + 16 * 2048 + nb + 32);
                }
            }
        }

        const short* Kb = Ksm + cur * 4096;
        floatx4 sa[4], sb[4];
        #pragma unroll
        for (int kt = 0; kt < 4; ++kt) {
            short8 kf0 = *reinterpret_cast<const short8*>(Kb + (kt * 16 + L15) * 64 + sk0);
            short8 kf1 = *reinterpret_cast<const short8*>(Kb + (kt * 16 + L15) * 64 + sk1);
            sa[kt] = {};
            sa[kt] = mfma16(aq0a, kf0, sa[kt]);
            sa[kt] = mfma16(aq1a, kf1, sa[kt]);
            sb[kt] = {};
            sb[kt] = mfma16(aq0b, kf0, sb[kt]);
            sb[kt] = mfma16(aq1b, kf1, sb[kt]);
        }

        #pragma unroll
        for (int r = 0; r < 4; ++r) {
            float e0 = fexp2(MASKED ? sa[0][r] + mc0a[r].x : sa[0][r]);
            float e1 = fexp2(MASKED ? sa[1][r] + mc0a[r].y : sa[1][r]);
            float e2 = fexp2(MASKED ? sa[2][r] + mc1a[r].x : sa[2][r]);
            float e3 = fexp2(MASKED ? sa[3][r] + mc1a[r].y : sa[3][r]);
            la[r] += (e0 + e1) + (e2 + e3);
            *reinterpret_cast<unsigned*>(&Pw[(g * 4 + r) * 72 + 2 * L15])      = bfpack(e0, e1);
            *reinterpret_cast<unsigned*>(&Pw[(g * 4 + r) * 72 + 32 + 2 * L15]) = bfpack(e2, e3);
            float f0 = fexp2(MASKED ? sb[0][r] + mc0b[r].x : sb[0][r]);
            float f1 = fexp2(MASKED ? sb[1][r] + mc0b[r].y : sb[1][r]);
            float f2 = fexp2(MASKED ? sb[2][r] + mc1b[r].x : sb[2][r]);
            float f3 = fexp2(MASKED ? sb[3][r] + mc1b[r].y : sb[3][r]);
            lb[r] += (f0 + f1) + (f2 + f3);
            *reinterpret_cast<unsigned*>(&Pw[(16 + g * 4 + r) * 72 + 2 * L15])      = bfpack(f0, f1);
            *reinterpret_cast<unsigned*>(&Pw[(16 + g * 4 + r) * 72 + 32 + 2 * L15]) = bfpack(f2, f3);
        }
        short8 ap0a = *reinterpret_cast<const short8*>(&Pw[L15 * 72 + g * 8]);
        short8 ap1a = *reinterpret_cast<const short8*>(&Pw[L15 * 72 + 32 + g * 8]);
        short8 ap0b = *reinterpret_cast<const short8*>(&Pw[(16 + L15) * 72 + g * 8]);
        short8 ap1b = *reinterpret_cast<const short8*>(&Pw[(16 + L15) * 72 + 32 + g * 8]);
        const short* Vb0 = Vsm + cur * 4096;
        const short* Vb1 = Vb0 + 2048;
        #pragma unroll
        for (int t = 0; t < 4; ++t) {
            short8 vf0 = *reinterpret_cast<const short8*>(Vb0 + t * 512 + vp + sv);
            short8 vf1 = *reinterpret_cast<const short8*>(Vb1 + t * 512 + vp + sv);
            Oa[t] = mfma16(ap0a, vf0, Oa[t]);
            Oa[t] = mfma16(ap1a, vf1, Oa[t]);
            Ob[t] = mfma16(ap0b, vf0, Ob[t]);
            Ob[t] = mfma16(ap1b, vf1, Ob[t]);
        }

        if (MASKED && more) {
            #pragma unroll
            for (int r = 0; r < 4; ++r) {
                mc0a[r] = nmc0a[r]; mc1a[r] = nmc1a[r];
                mc0b[r] = nmc0b[r]; mc1b[r] = nmc1b[r];
            }
        }
    }

    float inva[4], invb[4];
    #pragma unroll
    for (int r = 0; r < 4; ++r) {
        float ls = la[r];
        ls += __shfl_xor(ls, 1);
        ls += __shfl_xor(ls, 2);
        ls += __shfl_xor(ls, 4);
        ls += __shfl_xor(ls, 8);
        inva[r] = 1.0f / ls;
        if (L15 == 0) inv_l[(size_t)bh * 2048 + qb + g * 4 + r] = inva[r];
        float lt = lb[r];
        lt += __shfl_xor(lt, 1);
        lt += __shfl_xor(lt, 2);
        lt += __shfl_xor(lt, 4);
        lt += __shfl_xor(lt, 8);
        invb[r] = 1.0f / lt;
        if (L15 == 0) inv_l[(size_t)bh * 2048 + qb + 16 + g * 4 + r] = invb[r];
    }
    #pragma unroll
    for (int t = 0; t < 4; ++t) {
        int col = h * 64 + t * 16 + L15;
        #pragma unroll
        for (int r = 0; r < 4; ++r) {
            size_t qra = qb + g * 4 + r;
            float gta = bf2f(G[((size_t)b * 2048 + qra) * 1024 + col]);
            att[((size_t)b * 2048 + qra) * 1024 + col] = f2bf(Oa[t][r] * inva[r] * gta);
            size_t qrb = qb + 16 + g * 4 + r;
            float gtb = bf2f(G[((size_t)b * 2048 + qrb) * 1024 + col]);
            att[((size_t)b * 2048 + qrb) * 1024 + col] = f2bf(Ob[t][r] * invb[r] * gtb);
        }
    }
}

__global__ __launch_bounds__(256, 2) void flash_attn(
    const short* __restrict__ Q, const short* __restrict__ K,
    const short* __restrict__ Vt, const short* __restrict__ G,
    const float* __restrict__ Mc, const int* __restrict__ flag,
    short* __restrict__ att, float* __restrict__ inv_l)
{
    __shared__ short Ksm[2 * 4096];   // [buf][64 keys x 64 dims]
    __shared__ short Vsm[2 * 4096];   // [buf][2 key-halves][64 dims x 32 keys]
    __shared__ short Psm[4 * 2304];   // [wave][32 x 72]
    if (*flag)
        flash_body<true>(Q, K, Vt, G, Mc, att, inv_l, Ksm, Vsm, Psm);
    else
        flash_body<false>(Q, K, Vt, G, Mc, att, inv_l, Ksm, Vsm, Psm);
}

// ---------------------------------------------------------------------------
// avg_attn body, templated on MASKED (unmasked path = bare exp2, no pm).
// ---------------------------------------------------------------------------
template<bool MASKED>
__device__ __forceinline__ void avg_body(
    const short* __restrict__ Q, const short* __restrict__ K,
    const float* __restrict__ inv_l, float* mca, short* KsmBase)
{
    const int tid = threadIdx.x;
    const int lane = tid & 63, wid = tid >> 6;
    const int L15 = lane & 15, g = lane >> 4;
    const int b = blockIdx.z;
    const int qb = blockIdx.y * 64 + wid * 16;
    const int ks = blockIdx.x * 128;

    float pm[4][2][4];
    if (MASKED) {
        #pragma unroll
        for (int c = 0; c < 4; ++c)
            #pragma unroll
            for (int r = 0; r < 4; ++r) {
                size_t qr = qb + g * 4 + r;
                float2 m = *reinterpret_cast<const float2*>(
                    mca + ((size_t)b * 2048 + qr) * 2048 + ks + c * 32 + 2 * L15);
                pm[c][0][r] = m.x;
                pm[c][1][r] = m.y;
            }
    }
    float av[4][2][4] = {};

    const int rowoff = lane >> 3;
    const int choff = ((lane & 7) ^ rowoff) * 8;
    const int x7 = L15 & 7;
    const int sk0 = (g ^ x7) * 8, sk1 = ((g ^ 4) ^ x7) * 8;
    short* kL[2] = { KsmBase + wid * 2048, KsmBase + 8192 + wid * 2048 };

    {
        const short* p = K + ((size_t)(b * 16) * 2048 + ks + wid * 32 + rowoff) * 64 + choff;
        #pragma unroll
        for (int j = 0; j < 4; ++j) glds16(p + j * 512, kL[0] + j * 512);
    }
    short8 aq0 = *reinterpret_cast<const short8*>(Q + ((size_t)(b * 16) * 2048 + qb + L15) * 64 + g * 8);
    short8 aq1 = *reinterpret_cast<const short8*>(Q + ((size_t)(b * 16) * 2048 + qb + L15) * 64 + 32 + g * 8);
    float iv[4];
    #pragma unroll
    for (int r = 0; r < 4; ++r) iv[r] = inv_l[(size_t)(b * 16) * 2048 + qb + g * 4 + r];

    for (int h = 0; h < 16; ++h) {
        __syncthreads();
        short8 naq0, naq1;
        float niv[4];
        if (h < 15) {
            int nbh = b * 16 + h + 1;
            const short* p = K + ((size_t)nbh * 2048 + ks + wid * 32 + rowoff) * 64 + choff;
            #pragma unroll
            for (int j = 0; j < 4; ++j) glds16(p + j * 512, kL[(h + 1) & 1] + j * 512);
            naq0 = *reinterpret_cast<const short8*>(Q + ((size_t)nbh * 2048 + qb + L15) * 64 + g * 8);
            naq1 = *reinterpret_cast<const short8*>(Q + ((size_t)nbh * 2048 + qb + L15) * 64 + 32 + g * 8);
            #pragma unroll
            for (int r = 0; r < 4; ++r) niv[r] = inv_l[(size_t)nbh * 2048 + qb + g * 4 + r];
        }

        const short* Kb = KsmBase + (h & 1) * 8192;
        #pragma unroll
        for (int c = 0; c < 4; ++c) {
            const short* kbase = Kb + c * 32 * 64;
            floatx4 s0 = {}, s1 = {};
            s0 = mfma16(aq0, *reinterpret_cast<const short8*>(kbase + L15 * 64 + sk0), s0);
            s0 = mfma16(aq1, *reinterpret_cast<const short8*>(kbase + L15 * 64 + sk1), s0);
            s1 = mfma16(aq0, *reinterpret_cast<const short8*>(kbase + (16 + L15) * 64 + sk0), s1);
            s1 = mfma16(aq1, *reinterpret_cast<const short8*>(kbase + (16 + L15) * 64 + sk1), s1);
            #pragma unroll
            for (int r = 0; r < 4; ++r) {
                av[c][0][r] += fexp2(MASKED ? s0[r] + pm[c][0][r] : s0[r]) * iv[r];
                av[c][1][r] += fexp2(MASKED ? s1[r] + pm[c][1][r] : s1[r]) * iv[r];
            }
        }
        if (h < 15) {
            aq0 = naq0; aq1 = naq1;
            #pragma unroll
            for (int r = 0; r < 4; ++r) iv[r] = niv[r];
        }
    }
    #pragma unroll
    for (int c = 0; c < 4; ++c)
        #pragma unroll
        for (int t = 0; t < 2; ++t)
            #pragma unroll
            for (int r = 0; r < 4; ++r) {
                size_t qr = qb + g * 4 + r;
                int col = ks + c * 32 + t * 16 + L15;
                mca[((size_t)b * 2048 + qr) * 2048 + col] = av[c][t][r] * 0.0625f;
            }
}

__global__ __launch_bounds__(256) void avg_attn_kernel(
    const short* __restrict__ Q, const short* __restrict__ K,
    const float* __restrict__ inv_l, float* mca, const int* __restrict__ flag)
{
    __shared__ short Ksm[2 * 128 * 64];
    if (*flag)
        avg_body<true>(Q, K, inv_l, mca, Ksm);
    else
        avg_body<false>(Q, K, inv_l, mca, Ksm);
}

// ---------------------------------------------------------------------------
extern "C" void kernel_launch(void* const* d_in, const int* in_sizes, int n_in,
                              void* d_out, int out_size, void* d_ws, size_t ws_size,
                              hipStream_t stream)
{
    const float* x  = (const float*)d_in[0];
    const float* amask = (const float*)d_in[1];
    const unsigned char* kpm = (const unsigned char*)d_in[2];
    const float* Wq = (const float*)d_in[3];
    const float* bq = (const float*)d_in[4];
    const float* Wk = (const float*)d_in[5];
    const float* bk = (const float*)d_in[6];
    const float* Wv = (const float*)d_in[7];
    const float* bv = (const float*)d_in[8];
    const float* Wg = (const float*)d_in[9];
    const float* bg = (const float*)d_in[10];
    const float* Wo = (const float*)d_in[11];
    const float* bo = (const float*)d_in[12];

    char* ws = (char*)d_ws;
    const size_t MB = 1u << 20;
    short* Xb    = (short*)(ws);                 // 8 MB bf16 x (reused as Att)
    short* Att   = Xb;
    short* Qw    = (short*)(ws + 8 * MB);        // [bh][2048][64] (pre-scaled)
    short* Kw    = (short*)(ws + 16 * MB);       // [bh][2048][64]
    short* Vt    = (short*)(ws + 24 * MB);       // [bh][64][2048] (key-permuted)
    short* Gw    = (short*)(ws + 32 * MB);       // bf16 gate [m][1024]
    short* Wt    = (short*)(ws + 40 * MB);       // 5 x [1024n][1024k] bf16
    float* stats = (float*)(ws + 50 * MB);       // inv_l (256 KB)
    int*   flagp = (int*)(ws + 50 * MB + 262144);

    float* outp = (float*)d_out;                 // [2][2048][1024]
    float* avgp = (float*)d_out + 4194304;       // [2][2048][2048]; holds Mc first

    hipMemsetAsync(flagp, 0, sizeof(int), stream);

    flag_scan<<<2048, 256, 0, stream>>>(amask, kpm, flagp);

    cvt_x_kernel<<<2048, 256, 0, stream>>>(x, Xb, 524288);
    cvt_wt_kernel<<<dim3(16, 16, 5), 256, 0, stream>>>(Wq, Wk, Wv, Wg, Wo, Wt);
    mask_prep<<<dim3(1, 2048, 2), 256, 0, stream>>>(amask, kpm, avgp, flagp);

    qkvg_gemm<<<256, 512, 0, stream>>>(Xb, Wt, bq, bk, bv, bg, Qw, Kw, Vt, Gw);

    flash_attn<<<dim3(16, 16, 2), 256, 0, stream>>>(Qw, Kw, Vt, Gw, avgp, flagp, Att, stats);

    avg_attn_kernel<<<dim3(16, 32, 2), 256, 0, stream>>>(Qw, Kw, stats, avgp, flagp);

    out_gemm<<<dim3(8, 32), 256, 0, stream>>>(Att, Wt + 4 * 1048576, bo, outp);
}